// Round 7
// baseline (150.241 us; speedup 1.0000x reference)
//
#include <hip/hip_runtime.h>

#define NHEAD 16
#define DHEAD 64
#define SEQ 2048
#define DMODEL 1024
#define BATCH 2
#define QSCALE 0.1803368801111204f  // 0.125 * log2(e): softmax runs in exp2 domain

typedef __bf16 bf16x8 __attribute__((ext_vector_type(8)));
typedef float f32x4 __attribute__((ext_vector_type(4)));
typedef float f32x16 __attribute__((ext_vector_type(16)));
typedef unsigned int u32x4 __attribute__((ext_vector_type(4)));

__device__ inline unsigned short f2bf(float f) {
  unsigned int u = __builtin_bit_cast(unsigned int, f);
  u = (u + 0x7FFFu + ((u >> 16) & 1u)) >> 16;
  return (unsigned short)u;
}

__device__ inline unsigned int cvtpk_bf16(float lo, float hi) {
  unsigned int r;
  asm("v_cvt_pk_bf16_f32 %0, %1, %2" : "=v"(r) : "v"(lo), "v"(hi));
  return r;
}

__device__ inline void pl32swap(unsigned int& a, unsigned int& b) {
  asm volatile("v_permlane32_swap_b32 %0, %1" : "+v"(a), "+v"(b));
}

typedef __attribute__((address_space(1))) unsigned int GU32;
typedef __attribute__((address_space(3))) unsigned int LU32;
__device__ inline void gld_lds16(const void* g, void* l) {
  __builtin_amdgcn_global_load_lds((GU32*)g, (LU32*)l, 16, 0, 0);
}

// ---------------- convert x to bf16 ----------------
__global__ __launch_bounds__(256) void k_conv_x(const float* __restrict__ x,
                                                unsigned short* __restrict__ xb) {
  int i = blockIdx.x * 256 + threadIdx.x;
  float4 v = ((const float4*)x)[i];
  ushort4 o;
  o.x = f2bf(v.x); o.y = f2bf(v.y); o.z = f2bf(v.z); o.w = f2bf(v.w);
  ((ushort4*)xb)[i] = o;
}

// ---------------- transpose weights to N-major bf16 ----------------
__global__ __launch_bounds__(256) void k_trans_w(const float* __restrict__ Wq, const float* __restrict__ Wk,
                                                 const float* __restrict__ Wv, const float* __restrict__ Wo,
                                                 unsigned short* __restrict__ Wqt, unsigned short* __restrict__ Wkt,
                                                 unsigned short* __restrict__ Wvt, unsigned short* __restrict__ Wot) {
  __shared__ float ts[64][65];
  int z = blockIdx.z;
  const float* src = (z == 0) ? Wq : (z == 1) ? Wk : (z == 2) ? Wv : Wo;
  unsigned short* dst = (z == 0) ? Wqt : (z == 1) ? Wkt : (z == 2) ? Wvt : Wot;
  int r0 = blockIdx.y * 64, c0 = blockIdx.x * 64;
  int t = threadIdx.x;
  int tr = t >> 4, tc = (t & 15) * 4;
#pragma unroll
  for (int i = 0; i < 4; i++) {
    int row = tr + i * 16;
    float4 v = *(const float4*)&src[(size_t)(r0 + row) * DMODEL + c0 + tc];
    ts[row][tc + 0] = v.x; ts[row][tc + 1] = v.y; ts[row][tc + 2] = v.z; ts[row][tc + 3] = v.w;
  }
  __syncthreads();
#pragma unroll
  for (int i = 0; i < 4; i++) {
    int nrow = tr + i * 16;
    ushort4 o;
    o.x = f2bf(ts[tc + 0][nrow]); o.y = f2bf(ts[tc + 1][nrow]);
    o.z = f2bf(ts[tc + 2][nrow]); o.w = f2bf(ts[tc + 3][nrow]);
    *(ushort4*)&dst[(size_t)(c0 + nrow) * DMODEL + r0 + tc] = o;
  }
}

// ---------------- GEMM core: 3-buffer ring, counted vmcnt, 1 barrier/iter ----------------
__device__ __forceinline__ void stage_tile(const unsigned short* __restrict__ A,
                                           const unsigned short* __restrict__ Bt,
                                           int brow0, int bcol0, int k0,
                                           unsigned short* As, unsigned short* Bs,
                                           int lane, int wave) {
#pragma unroll
  for (int qi = 0; qi < 2; ++qi) {
    int e0 = (wave * 2 + qi) * 512;
    int e = e0 + lane * 8;
    gld_lds16(&A[(size_t)(brow0 + (e >> 5)) * DMODEL + k0 + (e & 31)], &As[e0]);
    gld_lds16(&Bt[(size_t)(bcol0 + (e >> 5)) * DMODEL + k0 + (e & 31)], &Bs[e0]);
  }
}

__device__ inline void gemm_ring(const unsigned short* __restrict__ A, const unsigned short* __restrict__ Bt,
                                 int brow0, int bcol0, unsigned short* AsBase, unsigned short* BsBase,
                                 f32x4 acc[4][4]) {
  const int NT = DMODEL / 32;  // 32 K-tiles
  int tid = threadIdx.x, lane = tid & 63, wave = tid >> 6;
  int wr = wave >> 1, wc = wave & 1;
  unsigned short* As[3] = {AsBase, AsBase + 4096, AsBase + 8192};
  unsigned short* Bs[3] = {BsBase, BsBase + 4096, BsBase + 8192};
  // prologue: stage tiles 0 and 1
  stage_tile(A, Bt, brow0, bcol0, 0, As[0], Bs[0], lane, wave);
  stage_tile(A, Bt, brow0, bcol0, 32, As[1], Bs[1], lane, wave);
  int cur = 0;
#pragma unroll 1
  for (int kt = 0; kt < NT; ++kt) {
    // tile kt (staged 2 iters ago) must have landed; newest stage (kt+1) may fly.
    if (kt < NT - 1) asm volatile("s_waitcnt vmcnt(4)" ::: "memory");
    else             asm volatile("s_waitcnt vmcnt(0)" ::: "memory");
    __builtin_amdgcn_s_barrier();
    unsigned short* Ac = As[cur];
    unsigned short* Bc = Bs[cur];
    bf16x8 af[4], bff[4];
#pragma unroll
    for (int i = 0; i < 4; i++)
      af[i] = *(const bf16x8*)&Ac[(wr * 64 + i * 16 + (lane & 15)) * 32 + (lane >> 4) * 8];
#pragma unroll
    for (int j = 0; j < 4; j++)
      bff[j] = *(const bf16x8*)&Bc[(wc * 64 + j * 16 + (lane & 15)) * 32 + (lane >> 4) * 8];
    if (kt + 2 < NT) {  // issue next-next stage; lands under >=2 iters of compute
      int nxt = cur + 2; if (nxt >= 3) nxt -= 3;
      stage_tile(A, Bt, brow0, bcol0, (kt + 2) * 32, As[nxt], Bs[nxt], lane, wave);
    }
#pragma unroll
    for (int i = 0; i < 4; i++)
#pragma unroll
      for (int j = 0; j < 4; j++)
        acc[i][j] = __builtin_amdgcn_mfma_f32_16x16x32_bf16(af[i], bff[j], acc[i][j], 0, 0, 0);
    cur = (cur + 1 == 3) ? 0 : cur + 1;
  }
}

// ---------------- fused QKV projection (XCD-chunked swizzle) ----------------
__global__ __launch_bounds__(256) void k_gemm_qkv(const unsigned short* __restrict__ xb,
                                                  const unsigned short* __restrict__ Wqt,
                                                  const unsigned short* __restrict__ Wkt,
                                                  const unsigned short* __restrict__ Wvt,
                                                  unsigned short* __restrict__ Qb,
                                                  unsigned short* __restrict__ Kb,
                                                  unsigned short* __restrict__ Vtb) {
  __shared__ unsigned short As[3 * 4096];
  __shared__ unsigned short Bs[3 * 4096];
  int hw = blockIdx.x;                    // 768 blocks
  int lin = (hw & 7) * 96 + (hw >> 3);    // each XCD: 4 row-panels x 24 col-blocks
  int by = lin / 24, bxx = lin % 24;
  int wsel = bxx >> 3;
  int col0 = (bxx & 7) * 128;
  int brow0 = by * 128;
  const unsigned short* Bt = (wsel == 0) ? Wqt : (wsel == 1) ? Wkt : Wvt;
  int lane = threadIdx.x & 63, wave = threadIdx.x >> 6;
  int wr = wave >> 1, wc = wave & 1;
  f32x4 acc[4][4] = {};
  gemm_ring(xb, Bt, brow0, col0, As, Bs, acc);
#pragma unroll
  for (int i = 0; i < 4; i++)
#pragma unroll
    for (int j = 0; j < 4; j++) {
      int rowb = brow0 + wr * 64 + i * 16 + ((lane >> 4) << 2);
      int c = col0 + wc * 64 + j * 16 + (lane & 15);
      int b = rowb >> 11, n0 = rowb & 2047;
      int h = c >> 6, d = c & 63;
      if (wsel == 2) {
        ushort4 o;
        o.x = f2bf(acc[i][j][0]); o.y = f2bf(acc[i][j][1]);
        o.z = f2bf(acc[i][j][2]); o.w = f2bf(acc[i][j][3]);
        *(ushort4*)&Vtb[((size_t)(b * NHEAD + h) * DHEAD + d) * SEQ + n0] = o;
      } else {
#pragma unroll
        for (int r = 0; r < 4; r++) {
          size_t idx = ((size_t)(b * NHEAD + h) * SEQ + (n0 + r)) * DHEAD + d;
          if (wsel == 0) Qb[idx] = f2bf(acc[i][j][r] * QSCALE);
          else           Kb[idx] = f2bf(acc[i][j][r]);
        }
      }
    }
}

// ---------------- flash attention (causal): unchanged from round 6 ----------------
#define KPAD 68
__global__ __launch_bounds__(128, 2) void k_attn(const unsigned short* __restrict__ Qb,
                                                 const unsigned short* __restrict__ Kb,
                                                 const unsigned short* __restrict__ Vtb,
                                                 unsigned short* __restrict__ Ob) {
  __shared__ unsigned short Ks[2][64 * KPAD];
  __shared__ unsigned short Vs[2][64 * KPAD];
  int id = blockIdx.x;
  int xcd = id & 7, loc = id >> 3;
  int bh2 = loc >> 5, jj = loc & 31;
  int bh = xcd * 4 + bh2;
  int pr = (jj + bh2 * 8) & 31;
  int tid = threadIdx.x, wv = tid >> 6, lane = tid & 63;
  int h = lane >> 5, ql = lane & 31;
  int v = wv ? pr : (63 - pr);
  int dcn = v >> 1;
  int nk = ((63 - pr) >> 1) + 1;
  int qrow = v * 32 + ql;
  int sr = tid >> 3, sc = (tid & 7) * 8;

  const unsigned short* Qh = Qb + (size_t)bh * SEQ * DHEAD;
  const unsigned short* Kh = Kb + (size_t)bh * SEQ * DHEAD;
  const unsigned short* Vh = Vtb + (size_t)bh * DHEAD * SEQ;
  int b = bh >> 4, hh = bh & 15;

  bf16x8 qf[4];
#pragma unroll
  for (int ds = 0; ds < 4; ds++)
    qf[ds] = *(const bf16x8*)&Qh[(size_t)qrow * DHEAD + ds * 16 + 8 * h];

  f32x16 o0 = {}, o1 = {};
  float m_r = -3.0e38f, l_r = 0.0f;

#pragma unroll
  for (int rj = 0; rj < 4; rj++) {
    int row = rj * 16 + sr;
    *(bf16x8*)&Ks[0][row * KPAD + sc] = *(const bf16x8*)&Kh[(size_t)row * DHEAD + sc];
    *(bf16x8*)&Vs[0][row * KPAD + sc] = *(const bf16x8*)&Vh[(size_t)row * SEQ + sc];
  }
  __syncthreads();

#pragma unroll 1
  for (int kc = 0; kc < nk; ++kc) {
    int cur = kc & 1;
    bool pfn = (kc + 1 < nk);
    bf16x8 kpre[4], vpre[4];
    if (pfn) {
      int kn = (kc + 1) * 64;
#pragma unroll
      for (int rj = 0; rj < 4; rj++) {
        int row = rj * 16 + sr;
        kpre[rj] = *(const bf16x8*)&Kh[(size_t)(kn + row) * DHEAD + sc];
        vpre[rj] = *(const bf16x8*)&Vh[(size_t)row * SEQ + kn + sc];
      }
    }

    if (kc <= dcn) {
      f32x16 s0 = {}, s1 = {};
#pragma unroll
      for (int ds = 0; ds < 4; ds++) {
        bf16x8 kf0 = *(const bf16x8*)&Ks[cur][ql * KPAD + ds * 16 + 8 * h];
        bf16x8 kf1 = *(const bf16x8*)&Ks[cur][(32 + ql) * KPAD + ds * 16 + 8 * h];
        s0 = __builtin_amdgcn_mfma_f32_32x32x16_bf16(kf0, qf[ds], s0, 0, 0, 0);
        s1 = __builtin_amdgcn_mfma_f32_32x32x16_bf16(kf1, qf[ds], s1, 0, 0, 0);
      }
      int k0 = kc * 64;
      if (kc == dcn) {
#pragma unroll
        for (int r = 0; r < 16; r++) {
          int kloc = (r & 3) + 8 * (r >> 2) + 4 * h;
          if (k0 + kloc > qrow) s0[r] = -3.0e38f;
          if (k0 + 32 + kloc > qrow) s1[r] = -3.0e38f;
        }
      }
      float t0[8], t1[8];
#pragma unroll
      for (int r = 0; r < 8; r++) t0[r] = fmaxf(s0[r], s0[r + 8]);
#pragma unroll
      for (int r = 0; r < 8; r++) t1[r] = fmaxf(s1[r], s1[r + 8]);
#pragma unroll
      for (int r = 0; r < 4; r++) t0[r] = fmaxf(fmaxf(t0[r], t0[r + 4]), fmaxf(t1[r], t1[r + 4]));
      float pm = fmaxf(fmaxf(t0[0], t0[1]), fmaxf(t0[2], t0[3]));
      pm = fmaxf(pm, __shfl_xor(pm, 32));
      bool grow = pm > m_r + 8.0f;
      float mnew = grow ? pm : m_r;
      float sf = grow ? __builtin_amdgcn_exp2f(m_r - mnew) : 1.0f;
      m_r = mnew;
      float rsum = 0.0f;
#pragma unroll
      for (int r = 0; r < 16; r++) { s0[r] = __builtin_amdgcn_exp2f(s0[r] - m_r); rsum += s0[r]; }
#pragma unroll
      for (int r = 0; r < 16; r++) { s1[r] = __builtin_amdgcn_exp2f(s1[r] - m_r); rsum += s1[r]; }
      l_r = l_r * sf + rsum;
      if (__ballot(grow)) {
#pragma unroll
        for (int r = 0; r < 16; r++) { o0[r] *= sf; o1[r] *= sf; }
      }
      unsigned int pa0 = cvtpk_bf16(s0[0], s0[1]),   pa1 = cvtpk_bf16(s0[2], s0[3]);
      unsigned int pb0 = cvtpk_bf16(s0[4], s0[5]),   pb1 = cvtpk_bf16(s0[6], s0[7]);
      unsigned int pc0 = cvtpk_bf16(s0[8], s0[9]),   pc1 = cvtpk_bf16(s0[10], s0[11]);
      unsigned int pd0 = cvtpk_bf16(s0[12], s0[13]), pd1 = cvtpk_bf16(s0[14], s0[15]);
      unsigned int pe0 = cvtpk_bf16(s1[0], s1[1]),   pe1 = cvtpk_bf16(s1[2], s1[3]);
      unsigned int pf0 = cvtpk_bf16(s1[4], s1[5]),   pf1 = cvtpk_bf16(s1[6], s1[7]);
      unsigned int pg0 = cvtpk_bf16(s1[8], s1[9]),   pg1 = cvtpk_bf16(s1[10], s1[11]);
      unsigned int ph0 = cvtpk_bf16(s1[12], s1[13]), ph1 = cvtpk_bf16(s1[14], s1[15]);
      pl32swap(pa0, pb0); pl32swap(pa1, pb1);
      pl32swap(pc0, pd0); pl32swap(pc1, pd1);
      pl32swap(pe0, pf0); pl32swap(pe1, pf1);
      pl32swap(pg0, ph0); pl32swap(pg1, ph1);
      bf16x8 pfr[4];
      pfr[0] = __builtin_bit_cast(bf16x8, (u32x4){pa0, pa1, pb0, pb1});
      pfr[1] = __builtin_bit_cast(bf16x8, (u32x4){pc0, pc1, pd0, pd1});
      pfr[2] = __builtin_bit_cast(bf16x8, (u32x4){pe0, pe1, pf0, pf1});
      pfr[3] = __builtin_bit_cast(bf16x8, (u32x4){pg0, pg1, ph0, ph1});
#pragma unroll
      for (int ks = 0; ks < 4; ks++) {
        bf16x8 vf0 = *(const bf16x8*)&Vs[cur][ql * KPAD + ks * 16 + 8 * h];
        bf16x8 vf1 = *(const bf16x8*)&Vs[cur][(32 + ql) * KPAD + ks * 16 + 8 * h];
        o0 = __builtin_amdgcn_mfma_f32_32x32x16_bf16(vf0, pfr[ks], o0, 0, 0, 0);
        o1 = __builtin_amdgcn_mfma_f32_32x32x16_bf16(vf1, pfr[ks], o1, 0, 0, 0);
      }
    }

    if (pfn) {
#pragma unroll
      for (int rj = 0; rj < 4; rj++) {
        int row = rj * 16 + sr;
        *(bf16x8*)&Ks[cur ^ 1][row * KPAD + sc] = kpre[rj];
        *(bf16x8*)&Vs[cur ^ 1][row * KPAD + sc] = vpre[rj];
      }
    }
    __syncthreads();
  }

  float lt = l_r + __shfl_xor(l_r, 32);
  float rl = 1.0f / lt;
  size_t obase = ((size_t)(b * SEQ + qrow)) * DMODEL + hh * DHEAD;
#pragma unroll
  for (int rg = 0; rg < 4; rg++) {
    uint2 w0, w1;
    w0.x = cvtpk_bf16(o0[4 * rg] * rl, o0[4 * rg + 1] * rl);
    w0.y = cvtpk_bf16(o0[4 * rg + 2] * rl, o0[4 * rg + 3] * rl);
    w1.x = cvtpk_bf16(o1[4 * rg] * rl, o1[4 * rg + 1] * rl);
    w1.y = cvtpk_bf16(o1[4 * rg + 2] * rl, o1[4 * rg + 3] * rl);
    *(uint2*)&Ob[obase + 8 * rg + 4 * h] = w0;
    *(uint2*)&Ob[obase + 32 + 8 * rg + 4 * h] = w1;
  }
}

// ---------------- output projection (ring + XCD swizzle) ----------------
__global__ __launch_bounds__(256) void k_gemm_out(const unsigned short* __restrict__ Ob,
                                                  const unsigned short* __restrict__ Wot,
                                                  float* __restrict__ out) {
  __shared__ unsigned short As[3 * 4096];
  __shared__ unsigned short Bs[3 * 4096];
  int hw = blockIdx.x;                  // 256 blocks
  int lin = (hw & 7) * 32 + (hw >> 3);  // each XCD: 4 row-panels x 8 col-blocks
  int by = lin >> 3, bx = lin & 7;
  int col0 = bx * 128;
  int brow0 = by * 128;
  int lane = threadIdx.x & 63, wave = threadIdx.x >> 6;
  int wr = wave >> 1, wc = wave & 1;
  f32x4 acc[4][4] = {};
  gemm_ring(Ob, Wot, brow0, col0, As, Bs, acc);
#pragma unroll
  for (int i = 0; i < 4; i++)
#pragma unroll
    for (int j = 0; j < 4; j++)
#pragma unroll
      for (int r = 0; r < 4; r++) {
        int row = brow0 + wr * 64 + i * 16 + ((lane >> 4) << 2) + r;
        int c = col0 + wc * 64 + j * 16 + (lane & 15);
        out[(size_t)row * DMODEL + c] = acc[i][j][r];
      }
}

extern "C" void kernel_launch(void* const* d_in, const int* in_sizes, int n_in,
                              void* d_out, int out_size, void* d_ws, size_t ws_size,
                              hipStream_t stream) {
  const float* x  = (const float*)d_in[0];
  const float* Wq = (const float*)d_in[1];
  const float* Wk = (const float*)d_in[2];
  const float* Wv = (const float*)d_in[3];
  const float* Wo = (const float*)d_in[4];
  float* out = (float*)d_out;
  char* ws = (char*)d_ws;
  unsigned short* xb  = (unsigned short*)(ws);
  unsigned short* Wqt = (unsigned short*)(ws + (8ull << 20));
  unsigned short* Wkt = (unsigned short*)(ws + (10ull << 20));
  unsigned short* Wvt = (unsigned short*)(ws + (12ull << 20));
  unsigned short* Wot = (unsigned short*)(ws + (14ull << 20));
  unsigned short* Qb  = (unsigned short*)(ws + (16ull << 20));
  unsigned short* Kb  = (unsigned short*)(ws + (24ull << 20));
  unsigned short* Vtb = (unsigned short*)(ws + (32ull << 20));
  unsigned short* Ob  = (unsigned short*)(ws + (40ull << 20));

  k_conv_x<<<dim3(4096), dim3(256), 0, stream>>>(x, xb);
  k_trans_w<<<dim3(16, 16, 4), dim3(256), 0, stream>>>(Wq, Wk, Wv, Wo, Wqt, Wkt, Wvt, Wot);
  k_gemm_qkv<<<dim3(768), dim3(256), 0, stream>>>(xb, Wqt, Wkt, Wvt, Qb, Kb, Vtb);
  k_attn<<<dim3(1024), dim3(128), 0, stream>>>(Qb, Kb, Vtb, Ob);
  k_gemm_out<<<dim3(256), dim3(256), 0, stream>>>(Ob, Wot, out);
}

// Round 8
// 137.599 us; speedup vs baseline: 1.0919x; 1.0919x over previous
//
#include <hip/hip_runtime.h>

#define NHEAD 16
#define DHEAD 64
#define SEQ 2048
#define DMODEL 1024
#define BATCH 2
#define QSCALE 0.1803368801111204f  // 0.125 * log2(e): softmax runs in exp2 domain

typedef __bf16 bf16x8 __attribute__((ext_vector_type(8)));
typedef float f32x4 __attribute__((ext_vector_type(4)));
typedef float f32x16 __attribute__((ext_vector_type(16)));
typedef unsigned int u32x4 __attribute__((ext_vector_type(4)));

__device__ inline unsigned short f2bf(float f) {
  unsigned int u = __builtin_bit_cast(unsigned int, f);
  u = (u + 0x7FFFu + ((u >> 16) & 1u)) >> 16;
  return (unsigned short)u;
}

__device__ inline unsigned int cvtpk_bf16(float lo, float hi) {
  unsigned int r;
  asm("v_cvt_pk_bf16_f32 %0, %1, %2" : "=v"(r) : "v"(lo), "v"(hi));
  return r;
}

__device__ inline void pl32swap(unsigned int& a, unsigned int& b) {
  asm volatile("v_permlane32_swap_b32 %0, %1" : "+v"(a), "+v"(b));
}

typedef __attribute__((address_space(1))) unsigned int GU32;
typedef __attribute__((address_space(3))) unsigned int LU32;
__device__ inline void gld_lds16(const void* g, void* l) {
  __builtin_amdgcn_global_load_lds((GU32*)g, (LU32*)l, 16, 0, 0);
}

// ---------------- convert x to bf16 ----------------
__global__ __launch_bounds__(256) void k_conv_x(const float* __restrict__ x,
                                                unsigned short* __restrict__ xb) {
  int i = blockIdx.x * 256 + threadIdx.x;
  float4 v = ((const float4*)x)[i];
  ushort4 o;
  o.x = f2bf(v.x); o.y = f2bf(v.y); o.z = f2bf(v.z); o.w = f2bf(v.w);
  ((ushort4*)xb)[i] = o;
}

// ---------------- transpose weights to N-major bf16 ----------------
__global__ __launch_bounds__(256) void k_trans_w(const float* __restrict__ Wq, const float* __restrict__ Wk,
                                                 const float* __restrict__ Wv, const float* __restrict__ Wo,
                                                 unsigned short* __restrict__ Wqt, unsigned short* __restrict__ Wkt,
                                                 unsigned short* __restrict__ Wvt, unsigned short* __restrict__ Wot) {
  __shared__ float ts[64][65];
  int z = blockIdx.z;
  const float* src = (z == 0) ? Wq : (z == 1) ? Wk : (z == 2) ? Wv : Wo;
  unsigned short* dst = (z == 0) ? Wqt : (z == 1) ? Wkt : (z == 2) ? Wvt : Wot;
  int r0 = blockIdx.y * 64, c0 = blockIdx.x * 64;
  int t = threadIdx.x;
  int tr = t >> 4, tc = (t & 15) * 4;
#pragma unroll
  for (int i = 0; i < 4; i++) {
    int row = tr + i * 16;
    float4 v = *(const float4*)&src[(size_t)(r0 + row) * DMODEL + c0 + tc];
    ts[row][tc + 0] = v.x; ts[row][tc + 1] = v.y; ts[row][tc + 2] = v.z; ts[row][tc + 3] = v.w;
  }
  __syncthreads();
#pragma unroll
  for (int i = 0; i < 4; i++) {
    int nrow = tr + i * 16;
    ushort4 o;
    o.x = f2bf(ts[tc + 0][nrow]); o.y = f2bf(ts[tc + 1][nrow]);
    o.z = f2bf(ts[tc + 2][nrow]); o.w = f2bf(ts[tc + 3][nrow]);
    *(ushort4*)&dst[(size_t)(c0 + nrow) * DMODEL + r0 + tc] = o;
  }
}

// ---------------- GEMM core (m97-style, r6 proven) ----------------
__device__ inline void gemm_core(const unsigned short* __restrict__ A, const unsigned short* __restrict__ Bt,
                                 int brow0, int bcol0, unsigned short* As, unsigned short* Bs,
                                 f32x4 acc[4][4]) {
  int tid = threadIdx.x, lane = tid & 63, wave = tid >> 6;
  int wr = wave >> 1, wc = wave & 1;
  for (int kt = 0; kt < DMODEL / 32; ++kt) {
    int k0 = kt * 32;
    if (kt) __syncthreads();
#pragma unroll
    for (int qi = 0; qi < 2; ++qi) {
      int e0 = (wave * 2 + qi) * 512;
      int e = e0 + lane * 8;
      gld_lds16(&A[(size_t)(brow0 + (e >> 5)) * DMODEL + k0 + (e & 31)], &As[e0]);
      gld_lds16(&Bt[(size_t)(bcol0 + (e >> 5)) * DMODEL + k0 + (e & 31)], &Bs[e0]);
    }
    __syncthreads();
    bf16x8 af[4], bff[4];
#pragma unroll
    for (int i = 0; i < 4; i++)
      af[i] = *(const bf16x8*)&As[(wr * 64 + i * 16 + (lane & 15)) * 32 + (lane >> 4) * 8];
#pragma unroll
    for (int j = 0; j < 4; j++)
      bff[j] = *(const bf16x8*)&Bs[(wc * 64 + j * 16 + (lane & 15)) * 32 + (lane >> 4) * 8];
#pragma unroll
    for (int i = 0; i < 4; i++)
#pragma unroll
      for (int j = 0; j < 4; j++)
        acc[i][j] = __builtin_amdgcn_mfma_f32_16x16x32_bf16(af[i], bff[j], acc[i][j], 0, 0, 0);
  }
}

// ---------------- fused QKV projection (r6 grid, natural dispatch) ----------------
__global__ __launch_bounds__(256) void k_gemm_qkv(const unsigned short* __restrict__ xb,
                                                  const unsigned short* __restrict__ Wqt,
                                                  const unsigned short* __restrict__ Wkt,
                                                  const unsigned short* __restrict__ Wvt,
                                                  unsigned short* __restrict__ Qb,
                                                  unsigned short* __restrict__ Kb,
                                                  unsigned short* __restrict__ Vtb) {
  __shared__ unsigned short As[128 * 32];
  __shared__ unsigned short Bs[128 * 32];
  int bx = blockIdx.x;
  int wsel = bx >> 3;
  int col0 = (bx & 7) * 128;
  int brow0 = blockIdx.y * 128;
  const unsigned short* Bt = (wsel == 0) ? Wqt : (wsel == 1) ? Wkt : Wvt;
  int lane = threadIdx.x & 63, wave = threadIdx.x >> 6;
  int wr = wave >> 1, wc = wave & 1;
  f32x4 acc[4][4] = {};
  gemm_core(xb, Bt, brow0, col0, As, Bs, acc);
#pragma unroll
  for (int i = 0; i < 4; i++)
#pragma unroll
    for (int j = 0; j < 4; j++) {
      int rowb = brow0 + wr * 64 + i * 16 + ((lane >> 4) << 2);
      int c = col0 + wc * 64 + j * 16 + (lane & 15);
      int b = rowb >> 11, n0 = rowb & 2047;
      int h = c >> 6, d = c & 63;
      if (wsel == 2) {
        ushort4 o;
        o.x = f2bf(acc[i][j][0]); o.y = f2bf(acc[i][j][1]);
        o.z = f2bf(acc[i][j][2]); o.w = f2bf(acc[i][j][3]);
        *(ushort4*)&Vtb[((size_t)(b * NHEAD + h) * DHEAD + d) * SEQ + n0] = o;
      } else {
#pragma unroll
        for (int r = 0; r < 4; r++) {
          size_t idx = ((size_t)(b * NHEAD + h) * SEQ + (n0 + r)) * DHEAD + d;
          if (wsel == 0) Qb[idx] = f2bf(acc[i][j][r] * QSCALE);
          else           Kb[idx] = f2bf(acc[i][j][r]);
        }
      }
    }
}

// ---------------- flash attention (causal): equal-length wave pairs ----------------
// Q,K: [bh][n][64] bf16 (Q pre-scaled by 0.125*log2e); V: [bh][64][n]; Ob: [b][n][h*64]
// Block = pair of ADJACENT 32-row q-tiles (2p, 2p+1): identical chunk range [0,p] ->
// both waves compute every chunk, zero barrier idle. Per-CU balance via p-alternation.
#define KPAD 68
__global__ __launch_bounds__(128, 2) void k_attn(const unsigned short* __restrict__ Qb,
                                                 const unsigned short* __restrict__ Kb,
                                                 const unsigned short* __restrict__ Vtb,
                                                 unsigned short* __restrict__ Ob) {
  __shared__ unsigned short Ks[2][64 * KPAD];
  __shared__ unsigned short Vs[2][64 * KPAD];
  int id = blockIdx.x;
  int xcd = id & 7, j = id >> 3;          // 128 blocks per XCD
  int bh2 = j >> 5, jj = j & 31;
  int bh = xcd * 4 + bh2;                 // 4 bh per XCD -> K/V L2-resident
  // alternate ascending/descending p across the 4 within-XCD rounds -> per-CU sum ~const
  int base = (bh2 & 2) ? ((jj + 16) & 31) : jj;
  int p = (bh2 & 1) ? (31 - base) : base; // pair index: tiles (2p, 2p+1), chunks 0..p
  int tid = threadIdx.x, wv = tid >> 6, lane = tid & 63;
  int h = lane >> 5, ql = lane & 31;
  int v = 2 * p + wv;                     // this wave's 32-row q-tile
  int nk = p + 1;
  int qrow = v * 32 + ql;
  int sr = tid >> 3, sc = (tid & 7) * 8;  // coalesced staging: 8 threads per 128-B row

  const unsigned short* Qh = Qb + (size_t)bh * SEQ * DHEAD;
  const unsigned short* Kh = Kb + (size_t)bh * SEQ * DHEAD;
  const unsigned short* Vh = Vtb + (size_t)bh * DHEAD * SEQ;
  int b = bh >> 4, hh = bh & 15;

  bf16x8 qf[4];
#pragma unroll
  for (int ds = 0; ds < 4; ds++)
    qf[ds] = *(const bf16x8*)&Qh[(size_t)qrow * DHEAD + ds * 16 + 8 * h];

  f32x16 o0 = {}, o1 = {};
  float m_r = -3.0e38f, l_r = 0.0f;

  // stage chunk 0 -> buf 0
#pragma unroll
  for (int rj = 0; rj < 4; rj++) {
    int row = rj * 16 + sr;
    *(bf16x8*)&Ks[0][row * KPAD + sc] = *(const bf16x8*)&Kh[(size_t)row * DHEAD + sc];
    *(bf16x8*)&Vs[0][row * KPAD + sc] = *(const bf16x8*)&Vh[(size_t)row * SEQ + sc];
  }
  __syncthreads();

#pragma unroll 1
  for (int kc = 0; kc < nk; ++kc) {
    int cur = kc & 1;
    bool pfn = (kc + 1 < nk);
    bf16x8 kpre[4], vpre[4];
    if (pfn) {  // register prefetch of chunk kc+1 (coalesced)
      int kn = (kc + 1) * 64;
#pragma unroll
      for (int rj = 0; rj < 4; rj++) {
        int row = rj * 16 + sr;
        kpre[rj] = *(const bf16x8*)&Kh[(size_t)(kn + row) * DHEAD + sc];
        vpre[rj] = *(const bf16x8*)&Vh[(size_t)row * SEQ + kn + sc];
      }
    }

    // ---- S^T = K * Q^T ----
    f32x16 s0 = {}, s1 = {};
#pragma unroll
    for (int ds = 0; ds < 4; ds++) {
      bf16x8 kf0 = *(const bf16x8*)&Ks[cur][ql * KPAD + ds * 16 + 8 * h];
      bf16x8 kf1 = *(const bf16x8*)&Ks[cur][(32 + ql) * KPAD + ds * 16 + 8 * h];
      s0 = __builtin_amdgcn_mfma_f32_32x32x16_bf16(kf0, qf[ds], s0, 0, 0, 0);
      s1 = __builtin_amdgcn_mfma_f32_32x32x16_bf16(kf1, qf[ds], s1, 0, 0, 0);
    }
    int k0 = kc * 64;
    // ---- causal mask (diagonal chunk only) ----
    if (kc == nk - 1) {
#pragma unroll
      for (int r = 0; r < 16; r++) {
        int kloc = (r & 3) + 8 * (r >> 2) + 4 * h;
        if (k0 + kloc > qrow) s0[r] = -3.0e38f;
        if (k0 + 32 + kloc > qrow) s1[r] = -3.0e38f;
      }
    }
    // ---- online softmax (exp2 domain, defer-max THR=8; l_r per-lane partial) ----
    float t0[8], t1[8];
#pragma unroll
    for (int r = 0; r < 8; r++) t0[r] = fmaxf(s0[r], s0[r + 8]);
#pragma unroll
    for (int r = 0; r < 8; r++) t1[r] = fmaxf(s1[r], s1[r + 8]);
#pragma unroll
    for (int r = 0; r < 4; r++) t0[r] = fmaxf(fmaxf(t0[r], t0[r + 4]), fmaxf(t1[r], t1[r + 4]));
    float pm = fmaxf(fmaxf(t0[0], t0[1]), fmaxf(t0[2], t0[3]));
    pm = fmaxf(pm, __shfl_xor(pm, 32));
    bool grow = pm > m_r + 8.0f;
    float mnew = grow ? pm : m_r;
    float sf = grow ? __builtin_amdgcn_exp2f(m_r - mnew) : 1.0f;
    m_r = mnew;
    float rsum = 0.0f;
#pragma unroll
    for (int r = 0; r < 16; r++) { s0[r] = __builtin_amdgcn_exp2f(s0[r] - m_r); rsum += s0[r]; }
#pragma unroll
    for (int r = 0; r < 16; r++) { s1[r] = __builtin_amdgcn_exp2f(s1[r] - m_r); rsum += s1[r]; }
    l_r = l_r * sf + rsum;
    if (__ballot(grow)) {
#pragma unroll
      for (int r = 0; r < 16; r++) { o0[r] *= sf; o1[r] *= sf; }
    }
    // ---- P^T B-fragments in-register ----
    unsigned int pa0 = cvtpk_bf16(s0[0], s0[1]),   pa1 = cvtpk_bf16(s0[2], s0[3]);
    unsigned int pb0 = cvtpk_bf16(s0[4], s0[5]),   pb1 = cvtpk_bf16(s0[6], s0[7]);
    unsigned int pc0 = cvtpk_bf16(s0[8], s0[9]),   pc1 = cvtpk_bf16(s0[10], s0[11]);
    unsigned int pd0 = cvtpk_bf16(s0[12], s0[13]), pd1 = cvtpk_bf16(s0[14], s0[15]);
    unsigned int pe0 = cvtpk_bf16(s1[0], s1[1]),   pe1 = cvtpk_bf16(s1[2], s1[3]);
    unsigned int pf0 = cvtpk_bf16(s1[4], s1[5]),   pf1 = cvtpk_bf16(s1[6], s1[7]);
    unsigned int pg0 = cvtpk_bf16(s1[8], s1[9]),   pg1 = cvtpk_bf16(s1[10], s1[11]);
    unsigned int ph0 = cvtpk_bf16(s1[12], s1[13]), ph1 = cvtpk_bf16(s1[14], s1[15]);
    pl32swap(pa0, pb0); pl32swap(pa1, pb1);
    pl32swap(pc0, pd0); pl32swap(pc1, pd1);
    pl32swap(pe0, pf0); pl32swap(pe1, pf1);
    pl32swap(pg0, ph0); pl32swap(pg1, ph1);
    bf16x8 pfr[4];
    pfr[0] = __builtin_bit_cast(bf16x8, (u32x4){pa0, pa1, pb0, pb1});
    pfr[1] = __builtin_bit_cast(bf16x8, (u32x4){pc0, pc1, pd0, pd1});
    pfr[2] = __builtin_bit_cast(bf16x8, (u32x4){pe0, pe1, pf0, pf1});
    pfr[3] = __builtin_bit_cast(bf16x8, (u32x4){pg0, pg1, ph0, ph1});
    // ---- O^T += V^T * P^T ----
#pragma unroll
    for (int ks = 0; ks < 4; ks++) {
      bf16x8 vf0 = *(const bf16x8*)&Vs[cur][ql * KPAD + ks * 16 + 8 * h];
      bf16x8 vf1 = *(const bf16x8*)&Vs[cur][(32 + ql) * KPAD + ks * 16 + 8 * h];
      o0 = __builtin_amdgcn_mfma_f32_32x32x16_bf16(vf0, pfr[ks], o0, 0, 0, 0);
      o1 = __builtin_amdgcn_mfma_f32_32x32x16_bf16(vf1, pfr[ks], o1, 0, 0, 0);
    }

    if (pfn) {  // write prefetched chunk into other buffer
#pragma unroll
      for (int rj = 0; rj < 4; rj++) {
        int row = rj * 16 + sr;
        *(bf16x8*)&Ks[cur ^ 1][row * KPAD + sc] = kpre[rj];
        *(bf16x8*)&Vs[cur ^ 1][row * KPAD + sc] = vpre[rj];
      }
    }
    __syncthreads();
  }

  // ---- epilogue: combine cross-half l, then O = O^T / l ----
  float lt = l_r + __shfl_xor(l_r, 32);
  float rl = 1.0f / lt;
  size_t obase = ((size_t)(b * SEQ + qrow)) * DMODEL + hh * DHEAD;
#pragma unroll
  for (int rg = 0; rg < 4; rg++) {
    uint2 w0, w1;
    w0.x = cvtpk_bf16(o0[4 * rg] * rl, o0[4 * rg + 1] * rl);
    w0.y = cvtpk_bf16(o0[4 * rg + 2] * rl, o0[4 * rg + 3] * rl);
    w1.x = cvtpk_bf16(o1[4 * rg] * rl, o1[4 * rg + 1] * rl);
    w1.y = cvtpk_bf16(o1[4 * rg + 2] * rl, o1[4 * rg + 3] * rl);
    *(uint2*)&Ob[obase + 8 * rg + 4 * h] = w0;
    *(uint2*)&Ob[obase + 32 + 8 * rg + 4 * h] = w1;
  }
}

// ---------------- output projection (r6 grid) ----------------
__global__ __launch_bounds__(256) void k_gemm_out(const unsigned short* __restrict__ Ob,
                                                  const unsigned short* __restrict__ Wot,
                                                  float* __restrict__ out) {
  __shared__ unsigned short As[128 * 32];
  __shared__ unsigned short Bs[128 * 32];
  int col0 = blockIdx.x * 128;
  int brow0 = blockIdx.y * 128;
  int lane = threadIdx.x & 63, wave = threadIdx.x >> 6;
  int wr = wave >> 1, wc = wave & 1;
  f32x4 acc[4][4] = {};
  gemm_core(Ob, Wot, brow0, col0, As, Bs, acc);
#pragma unroll
  for (int i = 0; i < 4; i++)
#pragma unroll
    for (int j = 0; j < 4; j++)
#pragma unroll
      for (int r = 0; r < 4; r++) {
        int row = brow0 + wr * 64 + i * 16 + ((lane >> 4) << 2) + r;
        int c = col0 + wc * 64 + j * 16 + (lane & 15);
        out[(size_t)row * DMODEL + c] = acc[i][j][r];
      }
}

extern "C" void kernel_launch(void* const* d_in, const int* in_sizes, int n_in,
                              void* d_out, int out_size, void* d_ws, size_t ws_size,
                              hipStream_t stream) {
  const float* x  = (const float*)d_in[0];
  const float* Wq = (const float*)d_in[1];
  const float* Wk = (const float*)d_in[2];
  const float* Wv = (const float*)d_in[3];
  const float* Wo = (const float*)d_in[4];
  float* out = (float*)d_out;
  char* ws = (char*)d_ws;
  unsigned short* xb  = (unsigned short*)(ws);
  unsigned short* Wqt = (unsigned short*)(ws + (8ull << 20));
  unsigned short* Wkt = (unsigned short*)(ws + (10ull << 20));
  unsigned short* Wvt = (unsigned short*)(ws + (12ull << 20));
  unsigned short* Wot = (unsigned short*)(ws + (14ull << 20));
  unsigned short* Qb  = (unsigned short*)(ws + (16ull << 20));
  unsigned short* Kb  = (unsigned short*)(ws + (24ull << 20));
  unsigned short* Vtb = (unsigned short*)(ws + (32ull << 20));
  unsigned short* Ob  = (unsigned short*)(ws + (40ull << 20));

  k_conv_x<<<dim3(4096), dim3(256), 0, stream>>>(x, xb);
  k_trans_w<<<dim3(16, 16, 4), dim3(256), 0, stream>>>(Wq, Wk, Wv, Wo, Wqt, Wkt, Wvt, Wot);
  k_gemm_qkv<<<dim3(24, 32), dim3(256), 0, stream>>>(xb, Wqt, Wkt, Wvt, Qb, Kb, Vtb);
  k_attn<<<dim3(1024), dim3(128), 0, stream>>>(Qb, Kb, Vtb, Ob);
  k_gemm_out<<<dim3(8, 32), dim3(256), 0, stream>>>(Ob, Wot, out);
}

// Round 9
// 124.157 us; speedup vs baseline: 1.2101x; 1.1083x over previous
//
#include <hip/hip_runtime.h>

#define NHEAD 16
#define DHEAD 64
#define SEQ 2048
#define DMODEL 1024
#define BATCH 2
#define QSCALE 0.1803368801111204f  // 0.125 * log2(e): softmax runs in exp2 domain

typedef __bf16 bf16x8 __attribute__((ext_vector_type(8)));
typedef float f32x4 __attribute__((ext_vector_type(4)));
typedef float f32x16 __attribute__((ext_vector_type(16)));
typedef unsigned int u32x4 __attribute__((ext_vector_type(4)));

__device__ inline unsigned short f2bf(float f) {
  unsigned int u = __builtin_bit_cast(unsigned int, f);
  u = (u + 0x7FFFu + ((u >> 16) & 1u)) >> 16;
  return (unsigned short)u;
}

__device__ inline unsigned int cvtpk_bf16(float lo, float hi) {
  unsigned int r;
  asm("v_cvt_pk_bf16_f32 %0, %1, %2" : "=v"(r) : "v"(lo), "v"(hi));
  return r;
}

__device__ inline void pl32swap(unsigned int& a, unsigned int& b) {
  asm volatile("v_permlane32_swap_b32 %0, %1" : "+v"(a), "+v"(b));
}

typedef __attribute__((address_space(1))) unsigned int GU32;
typedef __attribute__((address_space(3))) unsigned int LU32;
__device__ inline void gld_lds16(const void* g, void* l) {
  __builtin_amdgcn_global_load_lds((GU32*)g, (LU32*)l, 16, 0, 0);
}

// ---------------- convert x to bf16 ----------------
__global__ __launch_bounds__(256) void k_conv_x(const float* __restrict__ x,
                                                unsigned short* __restrict__ xb) {
  int i = blockIdx.x * 256 + threadIdx.x;
  float4 v = ((const float4*)x)[i];
  ushort4 o;
  o.x = f2bf(v.x); o.y = f2bf(v.y); o.z = f2bf(v.z); o.w = f2bf(v.w);
  ((ushort4*)xb)[i] = o;
}

// ---------------- transpose weights to N-major bf16 ----------------
__global__ __launch_bounds__(256) void k_trans_w(const float* __restrict__ Wq, const float* __restrict__ Wk,
                                                 const float* __restrict__ Wv, const float* __restrict__ Wo,
                                                 unsigned short* __restrict__ Wqt, unsigned short* __restrict__ Wkt,
                                                 unsigned short* __restrict__ Wvt, unsigned short* __restrict__ Wot) {
  __shared__ float ts[64][65];
  int z = blockIdx.z;
  const float* src = (z == 0) ? Wq : (z == 1) ? Wk : (z == 2) ? Wv : Wo;
  unsigned short* dst = (z == 0) ? Wqt : (z == 1) ? Wkt : (z == 2) ? Wvt : Wot;
  int r0 = blockIdx.y * 64, c0 = blockIdx.x * 64;
  int t = threadIdx.x;
  int tr = t >> 4, tc = (t & 15) * 4;
#pragma unroll
  for (int i = 0; i < 4; i++) {
    int row = tr + i * 16;
    float4 v = *(const float4*)&src[(size_t)(r0 + row) * DMODEL + c0 + tc];
    ts[row][tc + 0] = v.x; ts[row][tc + 1] = v.y; ts[row][tc + 2] = v.z; ts[row][tc + 3] = v.w;
  }
  __syncthreads();
#pragma unroll
  for (int i = 0; i < 4; i++) {
    int nrow = tr + i * 16;
    ushort4 o;
    o.x = f2bf(ts[tc + 0][nrow]); o.y = f2bf(ts[tc + 1][nrow]);
    o.z = f2bf(ts[tc + 2][nrow]); o.w = f2bf(ts[tc + 3][nrow]);
    *(ushort4*)&dst[(size_t)(c0 + nrow) * DMODEL + r0 + tc] = o;
  }
}

// ---------------- GEMM core (m97-style, r6 proven) ----------------
__device__ inline void gemm_core(const unsigned short* __restrict__ A, const unsigned short* __restrict__ Bt,
                                 int brow0, int bcol0, unsigned short* As, unsigned short* Bs,
                                 f32x4 acc[4][4]) {
  int tid = threadIdx.x, lane = tid & 63, wave = tid >> 6;
  int wr = wave >> 1, wc = wave & 1;
  for (int kt = 0; kt < DMODEL / 32; ++kt) {
    int k0 = kt * 32;
    if (kt) __syncthreads();
#pragma unroll
    for (int qi = 0; qi < 2; ++qi) {
      int e0 = (wave * 2 + qi) * 512;
      int e = e0 + lane * 8;
      gld_lds16(&A[(size_t)(brow0 + (e >> 5)) * DMODEL + k0 + (e & 31)], &As[e0]);
      gld_lds16(&Bt[(size_t)(bcol0 + (e >> 5)) * DMODEL + k0 + (e & 31)], &Bs[e0]);
    }
    __syncthreads();
    bf16x8 af[4], bff[4];
#pragma unroll
    for (int i = 0; i < 4; i++)
      af[i] = *(const bf16x8*)&As[(wr * 64 + i * 16 + (lane & 15)) * 32 + (lane >> 4) * 8];
#pragma unroll
    for (int j = 0; j < 4; j++)
      bff[j] = *(const bf16x8*)&Bs[(wc * 64 + j * 16 + (lane & 15)) * 32 + (lane >> 4) * 8];
#pragma unroll
    for (int i = 0; i < 4; i++)
#pragma unroll
      for (int j = 0; j < 4; j++)
        acc[i][j] = __builtin_amdgcn_mfma_f32_16x16x32_bf16(af[i], bff[j], acc[i][j], 0, 0, 0);
  }
}

// ---------------- fused QKV projection: epilogue writes FRAGMENT-MAJOR layouts ----------------
// Qf[bh][v(64)][ds(4)][lane(64)][e(8)]   (tile=32 rows)
// Kf[bh][c(32)][jj(8)][lane(64)][e(8)]   jj = (d>>4) + 4*((n>>5)&1); lane = ((d>>3)&1)*32 + (n&31); e = d&7
// Vf[bh][c(32)][jj(8)][lane(64)][e(8)]   jj = ((n>>4)&3) + 4*(d>>5);  lane = ((n>>3)&1)*32 + (d&31); e = n&7
__global__ __launch_bounds__(256) void k_gemm_qkv(const unsigned short* __restrict__ xb,
                                                  const unsigned short* __restrict__ Wqt,
                                                  const unsigned short* __restrict__ Wkt,
                                                  const unsigned short* __restrict__ Wvt,
                                                  unsigned short* __restrict__ Qf,
                                                  unsigned short* __restrict__ Kf,
                                                  unsigned short* __restrict__ Vf) {
  __shared__ unsigned short As[128 * 32];
  __shared__ unsigned short Bs[128 * 32];
  int bx = blockIdx.x;
  int wsel = bx >> 3;
  int col0 = (bx & 7) * 128;
  int brow0 = blockIdx.y * 128;
  const unsigned short* Bt = (wsel == 0) ? Wqt : (wsel == 1) ? Wkt : Wvt;
  int lane = threadIdx.x & 63, wave = threadIdx.x >> 6;
  int wr = wave >> 1, wc = wave & 1;
  f32x4 acc[4][4] = {};
  gemm_core(xb, Bt, brow0, col0, As, Bs, acc);
#pragma unroll
  for (int i = 0; i < 4; i++)
#pragma unroll
    for (int j = 0; j < 4; j++) {
      int n_g = brow0 + wr * 64 + i * 16 + ((lane >> 4) << 2);
      int c = col0 + wc * 64 + j * 16 + (lane & 15);
      int b = n_g >> 11, n0 = n_g & 2047;
      int h = c >> 6, d = c & 63;
      int bh = b * NHEAD + h;
      if (wsel == 0) {
        size_t base = ((size_t)(bh * 64 + (n0 >> 5)) * 4 + (d >> 4)) * 512 +
                      (size_t)((((d >> 3) & 1) * 32 + (n0 & 31)) * 8 + (d & 7));
#pragma unroll
        for (int r = 0; r < 4; r++) Qf[base + 8 * r] = f2bf(acc[i][j][r] * QSCALE);
      } else if (wsel == 1) {
        size_t base = ((size_t)(bh * 32 + (n0 >> 6)) * 8 + ((d >> 4) + 4 * ((n0 >> 5) & 1))) * 512 +
                      (size_t)((((d >> 3) & 1) * 32 + (n0 & 31)) * 8 + (d & 7));
#pragma unroll
        for (int r = 0; r < 4; r++) Kf[base + 8 * r] = f2bf(acc[i][j][r]);
      } else {
        size_t base = ((size_t)(bh * 32 + (n0 >> 6)) * 8 + (((n0 >> 4) & 3) + 4 * (d >> 5))) * 512 +
                      (size_t)((((n0 >> 3) & 1) * 32 + (d & 31)) * 8 + (n0 & 7));
        ushort4 o;
        o.x = f2bf(acc[i][j][0]); o.y = f2bf(acc[i][j][1]);
        o.z = f2bf(acc[i][j][2]); o.w = f2bf(acc[i][j][3]);
        *(ushort4*)&Vf[base] = o;
      }
    }
}

// ---------------- flash attention (causal): 1 wave/block, fragment-major coalesced loads,
// no LDS, no barriers. 2048 blocks, ~2 waves/SIMD. ----------------
__global__ __launch_bounds__(64, 2) void k_attn(const unsigned short* __restrict__ Qf,
                                                const unsigned short* __restrict__ Kf,
                                                const unsigned short* __restrict__ Vf,
                                                unsigned short* __restrict__ Ob) {
  int id = blockIdx.x;
  int xcd = id & 7, m = id >> 3;          // 256 items per XCD (4 bh -> Kf+Vf 2MB L2-resident)
  int bhl = m & 3, u = m >> 2;            // u 0..63
  int bh = xcd * 4 + bhl;
  int v = (u < 32) ? (63 - u) : (u - 32); // long tiles dispatched first
  int nk = (v >> 1) + 1;
  int lane = threadIdx.x;
  int h = lane >> 5, ql = lane & 31;
  int qrow = v * 32 + ql;

  const unsigned short* Qp = Qf + (size_t)bh * 131072 + (size_t)v * 2048;
  const unsigned short* Kp = Kf + (size_t)bh * 131072;
  const unsigned short* Vp = Vf + (size_t)bh * 131072;
  int b = bh >> 4, hh = bh & 15;

  bf16x8 qv[4];
#pragma unroll
  for (int ds = 0; ds < 4; ds++)
    qv[ds] = *(const bf16x8*)&Qp[ds * 512 + lane * 8];

  bf16x8 Kr[8], Vr[8];
#pragma unroll
  for (int jj = 0; jj < 8; jj++) Kr[jj] = *(const bf16x8*)&Kp[jj * 512 + lane * 8];
#pragma unroll
  for (int jj = 0; jj < 8; jj++) Vr[jj] = *(const bf16x8*)&Vp[jj * 512 + lane * 8];

  f32x16 o0 = {}, o1 = {};
  float m_r = -3.0e38f, l_r = 0.0f;

#pragma unroll 1
  for (int kc = 0; kc < nk; ++kc) {
    // ---- S^T = K * Q^T ----
    f32x16 s0 = {}, s1 = {};
#pragma unroll
    for (int ds = 0; ds < 4; ds++) {
      s0 = __builtin_amdgcn_mfma_f32_32x32x16_bf16(Kr[ds], qv[ds], s0, 0, 0, 0);
      s1 = __builtin_amdgcn_mfma_f32_32x32x16_bf16(Kr[4 + ds], qv[ds], s1, 0, 0, 0);
    }
    bool pfn = (kc + 1 < nk);
    size_t nb = (size_t)(kc + 1) * 4096;
    if (pfn) {  // K regs free after QK^T: prefetch next chunk (lands during softmax+PV)
#pragma unroll
      for (int jj = 0; jj < 8; jj++) Kr[jj] = *(const bf16x8*)&Kp[nb + jj * 512 + lane * 8];
    }
    int k0 = kc * 64;
    // ---- causal mask (diagonal chunk only) ----
    if (kc == nk - 1) {
#pragma unroll
      for (int r = 0; r < 16; r++) {
        int kloc = (r & 3) + 8 * (r >> 2) + 4 * h;
        if (k0 + kloc > qrow) s0[r] = -3.0e38f;
        if (k0 + 32 + kloc > qrow) s1[r] = -3.0e38f;
      }
    }
    // ---- online softmax (exp2 domain, defer-max THR=8; l_r per-lane partial) ----
    float t0[8], t1[8];
#pragma unroll
    for (int r = 0; r < 8; r++) t0[r] = fmaxf(s0[r], s0[r + 8]);
#pragma unroll
    for (int r = 0; r < 8; r++) t1[r] = fmaxf(s1[r], s1[r + 8]);
#pragma unroll
    for (int r = 0; r < 4; r++) t0[r] = fmaxf(fmaxf(t0[r], t0[r + 4]), fmaxf(t1[r], t1[r + 4]));
    float pm = fmaxf(fmaxf(t0[0], t0[1]), fmaxf(t0[2], t0[3]));
    pm = fmaxf(pm, __shfl_xor(pm, 32));
    bool grow = pm > m_r + 8.0f;
    float mnew = grow ? pm : m_r;
    float sf = grow ? __builtin_amdgcn_exp2f(m_r - mnew) : 1.0f;
    m_r = mnew;
    float rsum = 0.0f;
#pragma unroll
    for (int r = 0; r < 16; r++) { s0[r] = __builtin_amdgcn_exp2f(s0[r] - m_r); rsum += s0[r]; }
#pragma unroll
    for (int r = 0; r < 16; r++) { s1[r] = __builtin_amdgcn_exp2f(s1[r] - m_r); rsum += s1[r]; }
    l_r = l_r * sf + rsum;
    if (__ballot(grow)) {
#pragma unroll
      for (int r = 0; r < 16; r++) { o0[r] *= sf; o1[r] *= sf; }
    }
    // ---- P^T B-fragments in-register ----
    unsigned int pa0 = cvtpk_bf16(s0[0], s0[1]),   pa1 = cvtpk_bf16(s0[2], s0[3]);
    unsigned int pb0 = cvtpk_bf16(s0[4], s0[5]),   pb1 = cvtpk_bf16(s0[6], s0[7]);
    unsigned int pc0 = cvtpk_bf16(s0[8], s0[9]),   pc1 = cvtpk_bf16(s0[10], s0[11]);
    unsigned int pd0 = cvtpk_bf16(s0[12], s0[13]), pd1 = cvtpk_bf16(s0[14], s0[15]);
    unsigned int pe0 = cvtpk_bf16(s1[0], s1[1]),   pe1 = cvtpk_bf16(s1[2], s1[3]);
    unsigned int pf0 = cvtpk_bf16(s1[4], s1[5]),   pf1 = cvtpk_bf16(s1[6], s1[7]);
    unsigned int pg0 = cvtpk_bf16(s1[8], s1[9]),   pg1 = cvtpk_bf16(s1[10], s1[11]);
    unsigned int ph0 = cvtpk_bf16(s1[12], s1[13]), ph1 = cvtpk_bf16(s1[14], s1[15]);
    pl32swap(pa0, pb0); pl32swap(pa1, pb1);
    pl32swap(pc0, pd0); pl32swap(pc1, pd1);
    pl32swap(pe0, pf0); pl32swap(pe1, pf1);
    pl32swap(pg0, ph0); pl32swap(pg1, ph1);
    bf16x8 pfr[4];
    pfr[0] = __builtin_bit_cast(bf16x8, (u32x4){pa0, pa1, pb0, pb1});
    pfr[1] = __builtin_bit_cast(bf16x8, (u32x4){pc0, pc1, pd0, pd1});
    pfr[2] = __builtin_bit_cast(bf16x8, (u32x4){pe0, pe1, pf0, pf1});
    pfr[3] = __builtin_bit_cast(bf16x8, (u32x4){pg0, pg1, ph0, ph1});
    // ---- O^T += V^T * P^T ----
#pragma unroll
    for (int ks = 0; ks < 4; ks++) {
      o0 = __builtin_amdgcn_mfma_f32_32x32x16_bf16(Vr[ks], pfr[ks], o0, 0, 0, 0);
      o1 = __builtin_amdgcn_mfma_f32_32x32x16_bf16(Vr[4 + ks], pfr[ks], o1, 0, 0, 0);
    }
    if (pfn) {  // V regs free after PV: prefetch next chunk (lands during next QK+softmax)
#pragma unroll
      for (int jj = 0; jj < 8; jj++) Vr[jj] = *(const bf16x8*)&Vp[nb + jj * 512 + lane * 8];
    }
  }

  // ---- epilogue: combine cross-half l, then O = O^T / l ----
  float lt = l_r + __shfl_xor(l_r, 32);
  float rl = 1.0f / lt;
  size_t obase = ((size_t)(b * SEQ + qrow)) * DMODEL + hh * DHEAD;
#pragma unroll
  for (int rg = 0; rg < 4; rg++) {
    uint2 w0, w1;
    w0.x = cvtpk_bf16(o0[4 * rg] * rl, o0[4 * rg + 1] * rl);
    w0.y = cvtpk_bf16(o0[4 * rg + 2] * rl, o0[4 * rg + 3] * rl);
    w1.x = cvtpk_bf16(o1[4 * rg] * rl, o1[4 * rg + 1] * rl);
    w1.y = cvtpk_bf16(o1[4 * rg + 2] * rl, o1[4 * rg + 3] * rl);
    *(uint2*)&Ob[obase + 8 * rg + 4 * h] = w0;
    *(uint2*)&Ob[obase + 32 + 8 * rg + 4 * h] = w1;
  }
}

// ---------------- output projection ----------------
__global__ __launch_bounds__(256) void k_gemm_out(const unsigned short* __restrict__ Ob,
                                                  const unsigned short* __restrict__ Wot,
                                                  float* __restrict__ out) {
  __shared__ unsigned short As[128 * 32];
  __shared__ unsigned short Bs[128 * 32];
  int col0 = blockIdx.x * 128;
  int brow0 = blockIdx.y * 128;
  int lane = threadIdx.x & 63, wave = threadIdx.x >> 6;
  int wr = wave >> 1, wc = wave & 1;
  f32x4 acc[4][4] = {};
  gemm_core(Ob, Wot, brow0, col0, As, Bs, acc);
#pragma unroll
  for (int i = 0; i < 4; i++)
#pragma unroll
    for (int j = 0; j < 4; j++)
#pragma unroll
      for (int r = 0; r < 4; r++) {
        int row = brow0 + wr * 64 + i * 16 + ((lane >> 4) << 2) + r;
        int c = col0 + wc * 64 + j * 16 + (lane & 15);
        out[(size_t)row * DMODEL + c] = acc[i][j][r];
      }
}

extern "C" void kernel_launch(void* const* d_in, const int* in_sizes, int n_in,
                              void* d_out, int out_size, void* d_ws, size_t ws_size,
                              hipStream_t stream) {
  const float* x  = (const float*)d_in[0];
  const float* Wq = (const float*)d_in[1];
  const float* Wk = (const float*)d_in[2];
  const float* Wv = (const float*)d_in[3];
  const float* Wo = (const float*)d_in[4];
  float* out = (float*)d_out;
  char* ws = (char*)d_ws;
  unsigned short* xb  = (unsigned short*)(ws);
  unsigned short* Wqt = (unsigned short*)(ws + (8ull << 20));
  unsigned short* Wkt = (unsigned short*)(ws + (10ull << 20));
  unsigned short* Wvt = (unsigned short*)(ws + (12ull << 20));
  unsigned short* Wot = (unsigned short*)(ws + (14ull << 20));
  unsigned short* Qf  = (unsigned short*)(ws + (16ull << 20));
  unsigned short* Kf  = (unsigned short*)(ws + (24ull << 20));
  unsigned short* Vf  = (unsigned short*)(ws + (32ull << 20));
  unsigned short* Ob  = (unsigned short*)(ws + (40ull << 20));

  k_conv_x<<<dim3(4096), dim3(256), 0, stream>>>(x, xb);
  k_trans_w<<<dim3(16, 16, 4), dim3(256), 0, stream>>>(Wq, Wk, Wv, Wo, Wqt, Wkt, Wvt, Wot);
  k_gemm_qkv<<<dim3(24, 32), dim3(256), 0, stream>>>(xb, Wqt, Wkt, Wvt, Qf, Kf, Vf);
  k_attn<<<dim3(2048), dim3(64), 0, stream>>>(Qf, Kf, Vf, Ob);
  k_gemm_out<<<dim3(8, 32), dim3(256), 0, stream>>>(Ob, Wot, out);
}

// Round 10
// 112.091 us; speedup vs baseline: 1.3403x; 1.1076x over previous
//
#include <hip/hip_runtime.h>

#define NHEAD 16
#define DHEAD 64
#define SEQ 2048
#define DMODEL 1024
#define BATCH 2
#define QSCALE 0.1803368801111204f  // 0.125 * log2(e): softmax runs in exp2 domain

typedef __bf16 bf16x8 __attribute__((ext_vector_type(8)));
typedef float f32x4 __attribute__((ext_vector_type(4)));
typedef float f32x16 __attribute__((ext_vector_type(16)));
typedef unsigned int u32x4 __attribute__((ext_vector_type(4)));

__device__ inline unsigned short f2bf(float f) {
  unsigned int u = __builtin_bit_cast(unsigned int, f);
  u = (u + 0x7FFFu + ((u >> 16) & 1u)) >> 16;
  return (unsigned short)u;
}

__device__ inline unsigned int cvtpk_bf16(float lo, float hi) {
  unsigned int r;
  asm("v_cvt_pk_bf16_f32 %0, %1, %2" : "=v"(r) : "v"(lo), "v"(hi));
  return r;
}

__device__ inline void pl32swap(unsigned int& a, unsigned int& b) {
  asm volatile("v_permlane32_swap_b32 %0, %1" : "+v"(a), "+v"(b));
}

typedef __attribute__((address_space(1))) unsigned int GU32;
typedef __attribute__((address_space(3))) unsigned int LU32;
__device__ inline void gld_lds16(const void* g, void* l) {
  __builtin_amdgcn_global_load_lds((GU32*)g, (LU32*)l, 16, 0, 0);
}

// ---------------- convert x to bf16, A-FRAGMENT-MAJOR ----------------
// Af[R(64)][kt(32)][i(4)][lane(64)][e(8)]: lane = ((k>>3)&3)*16 + (n&15), e = k&7, i = (n>>4)&3
__global__ __launch_bounds__(256) void k_conv_x(const float* __restrict__ x,
                                                unsigned short* __restrict__ Af) {
  int blk = blockIdx.x;           // 2048: R = blk>>5, kt = blk&31
  int R = blk >> 5, kt = blk & 31;
  int t = threadIdx.x;
  int i = t >> 6, lane = t & 63;
  int n = R * 64 + i * 16 + (lane & 15);
  int k = kt * 32 + (lane >> 4) * 8;
  const float* xp = x + (size_t)n * DMODEL + k;
  float4 v0 = *(const float4*)xp;
  float4 v1 = *(const float4*)(xp + 4);
  ushort4 lo, hi;
  lo.x = f2bf(v0.x); lo.y = f2bf(v0.y); lo.z = f2bf(v0.z); lo.w = f2bf(v0.w);
  hi.x = f2bf(v1.x); hi.y = f2bf(v1.y); hi.z = f2bf(v1.z); hi.w = f2bf(v1.w);
  size_t base = ((size_t)((R * 32 + kt) * 4 + i) * 64 + lane) * 8;
  *(ushort4*)&Af[base] = lo;
  *(ushort4*)&Af[base + 4] = hi;
}

// ---------------- Wq/Wk/Wv to B-FRAGMENT-MAJOR bf16 ----------------
// Wf[cb(16)][kt(32)][j(4)][lane(64)][e(8)]: lane = ((k>>3)&3)*16 + (c&15), e = k&7, j = (c>>4)&3
__global__ __launch_bounds__(256) void k_trans_wf(const float* __restrict__ Wq, const float* __restrict__ Wk,
                                                  const float* __restrict__ Wv,
                                                  unsigned short* __restrict__ Wqf, unsigned short* __restrict__ Wkf,
                                                  unsigned short* __restrict__ Wvf) {
  __shared__ float ts[32][65];
  int mat = blockIdx.z;
  const float* src = (mat == 0) ? Wq : (mat == 1) ? Wk : Wv;
  unsigned short* dst = (mat == 0) ? Wqf : (mat == 1) ? Wkf : Wvf;
  int cb = blockIdx.x, kt = blockIdx.y;
  int t = threadIdx.x;
  int row = t >> 3, seg = t & 7;
  const float* sp = src + (size_t)(kt * 32 + row) * DMODEL + cb * 64 + seg * 8;
  float4 u0 = *(const float4*)sp;
  float4 u1 = *(const float4*)(sp + 4);
  ts[row][seg * 8 + 0] = u0.x; ts[row][seg * 8 + 1] = u0.y;
  ts[row][seg * 8 + 2] = u0.z; ts[row][seg * 8 + 3] = u0.w;
  ts[row][seg * 8 + 4] = u1.x; ts[row][seg * 8 + 5] = u1.y;
  ts[row][seg * 8 + 6] = u1.z; ts[row][seg * 8 + 7] = u1.w;
  __syncthreads();
  int j = t >> 6, lane = t & 63;
  int c_l = j * 16 + (lane & 15);
  int kb = (lane >> 4) * 8;
  ushort4 lo, hi;
  lo.x = f2bf(ts[kb + 0][c_l]); lo.y = f2bf(ts[kb + 1][c_l]);
  lo.z = f2bf(ts[kb + 2][c_l]); lo.w = f2bf(ts[kb + 3][c_l]);
  hi.x = f2bf(ts[kb + 4][c_l]); hi.y = f2bf(ts[kb + 5][c_l]);
  hi.z = f2bf(ts[kb + 6][c_l]); hi.w = f2bf(ts[kb + 7][c_l]);
  size_t base = ((size_t)((cb * 32 + kt) * 4 + j) * 64 + lane) * 8;
  *(ushort4*)&dst[base] = lo;
  *(ushort4*)&dst[base + 4] = hi;
}

// ---------------- Wo transpose (old layout, for k_gemm_out) ----------------
__global__ __launch_bounds__(256) void k_trans_wo(const float* __restrict__ Wo,
                                                  unsigned short* __restrict__ Wot) {
  __shared__ float ts[64][65];
  int r0 = blockIdx.y * 64, c0 = blockIdx.x * 64;
  int t = threadIdx.x;
  int tr = t >> 4, tc = (t & 15) * 4;
#pragma unroll
  for (int i = 0; i < 4; i++) {
    int row = tr + i * 16;
    float4 v = *(const float4*)&Wo[(size_t)(r0 + row) * DMODEL + c0 + tc];
    ts[row][tc + 0] = v.x; ts[row][tc + 1] = v.y; ts[row][tc + 2] = v.z; ts[row][tc + 3] = v.w;
  }
  __syncthreads();
#pragma unroll
  for (int i = 0; i < 4; i++) {
    int nrow = tr + i * 16;
    ushort4 o;
    o.x = f2bf(ts[tc + 0][nrow]); o.y = f2bf(ts[tc + 1][nrow]);
    o.z = f2bf(ts[tc + 2][nrow]); o.w = f2bf(ts[tc + 3][nrow]);
    *(ushort4*)&Wot[(size_t)(c0 + nrow) * DMODEL + r0 + tc] = o;
  }
}

// ---------------- fused QKV projection: barrier-free fragment streaming ----------------
// 1 wave/block, 64x64 tile, zero LDS/barriers; register ping-pong prefetch.
// Grid 3072 = 8 XCD x [4 row-windows x 6 col x 16 rows]: working set/XCD ~2.8MB < 4MB L2.
__global__ __launch_bounds__(64, 2) void k_gemm_qkv(const unsigned short* __restrict__ Af,
                                                    const unsigned short* __restrict__ Wqf,
                                                    const unsigned short* __restrict__ Wkf,
                                                    const unsigned short* __restrict__ Wvf,
                                                    unsigned short* __restrict__ Qf,
                                                    unsigned short* __restrict__ Kf,
                                                    unsigned short* __restrict__ Vf) {
  int id = blockIdx.x;            // 3072
  int xcd = id & 7, lid = id >> 3;
  int rg = lid / 96, rem = lid - rg * 96;
  int cq = rem >> 4, rr = rem & 15;
  int R = rg * 16 + rr;           // 0..63 (64-row tile)
  int Cg = xcd * 6 + cq;          // 0..47 (64-col tile across 3 matrices)
  int mat = Cg >> 4, cb = Cg & 15;
  const unsigned short* Bf = (mat == 0) ? Wqf : (mat == 1) ? Wkf : Wvf;
  int lane = threadIdx.x;
  const unsigned short* Ap = Af + (size_t)R * 65536 + lane * 8;
  const unsigned short* Bp = Bf + (size_t)cb * 65536 + lane * 8;

  f32x4 acc[4][4] = {};
  bf16x8 a0[4], b0[4], a1[4], b1[4];
#pragma unroll
  for (int i = 0; i < 4; i++) {
    a0[i] = *(const bf16x8*)(Ap + i * 512);
    b0[i] = *(const bf16x8*)(Bp + i * 512);
  }
#pragma unroll 1
  for (int kt = 0; kt < 32; kt += 2) {
    {  // prefetch kt+1 into set 1 (kt even <= 30, so kt+1 always valid)
      const unsigned short* An = Ap + (kt + 1) * 2048;
      const unsigned short* Bn = Bp + (kt + 1) * 2048;
#pragma unroll
      for (int i = 0; i < 4; i++) {
        a1[i] = *(const bf16x8*)(An + i * 512);
        b1[i] = *(const bf16x8*)(Bn + i * 512);
      }
    }
#pragma unroll
    for (int i = 0; i < 4; i++)
#pragma unroll
      for (int j = 0; j < 4; j++)
        acc[i][j] = __builtin_amdgcn_mfma_f32_16x16x32_bf16(a0[i], b0[j], acc[i][j], 0, 0, 0);
    if (kt + 2 < 32) {  // prefetch kt+2 into set 0
      const unsigned short* An = Ap + (kt + 2) * 2048;
      const unsigned short* Bn = Bp + (kt + 2) * 2048;
#pragma unroll
      for (int i = 0; i < 4; i++) {
        a0[i] = *(const bf16x8*)(An + i * 512);
        b0[i] = *(const bf16x8*)(Bn + i * 512);
      }
    }
#pragma unroll
    for (int i = 0; i < 4; i++)
#pragma unroll
      for (int j = 0; j < 4; j++)
        acc[i][j] = __builtin_amdgcn_mfma_f32_16x16x32_bf16(a1[i], b1[j], acc[i][j], 0, 0, 0);
  }

  // ---- epilogue: fragment-major Qf/Kf/Vf writes (r9-verified formulas) ----
#pragma unroll
  for (int i = 0; i < 4; i++)
#pragma unroll
    for (int j = 0; j < 4; j++) {
      int n_g = R * 64 + i * 16 + ((lane >> 4) << 2);
      int c = cb * 64 + j * 16 + (lane & 15);   // within-matrix col 0..1023
      int b = n_g >> 11, n0 = n_g & 2047;
      int h = c >> 6, d = c & 63;
      int bh = b * NHEAD + h;
      if (mat == 0) {
        size_t base = ((size_t)(bh * 64 + (n0 >> 5)) * 4 + (d >> 4)) * 512 +
                      (size_t)((((d >> 3) & 1) * 32 + (n0 & 31)) * 8 + (d & 7));
#pragma unroll
        for (int r = 0; r < 4; r++) Qf[base + 8 * r] = f2bf(acc[i][j][r] * QSCALE);
      } else if (mat == 1) {
        size_t base = ((size_t)(bh * 32 + (n0 >> 6)) * 8 + ((d >> 4) + 4 * ((n0 >> 5) & 1))) * 512 +
                      (size_t)((((d >> 3) & 1) * 32 + (n0 & 31)) * 8 + (d & 7));
#pragma unroll
        for (int r = 0; r < 4; r++) Kf[base + 8 * r] = f2bf(acc[i][j][r]);
      } else {
        size_t base = ((size_t)(bh * 32 + (n0 >> 6)) * 8 + (((n0 >> 4) & 3) + 4 * (d >> 5))) * 512 +
                      (size_t)((((n0 >> 3) & 1) * 32 + (d & 31)) * 8 + (n0 & 7));
        ushort4 o;
        o.x = f2bf(acc[i][j][0]); o.y = f2bf(acc[i][j][1]);
        o.z = f2bf(acc[i][j][2]); o.w = f2bf(acc[i][j][3]);
        *(ushort4*)&Vf[base] = o;
      }
    }
}

// ---------------- GEMM core (m97-style) for output projection ----------------
__device__ inline void gemm_core(const unsigned short* __restrict__ A, const unsigned short* __restrict__ Bt,
                                 int brow0, int bcol0, unsigned short* As, unsigned short* Bs,
                                 f32x4 acc[4][4]) {
  int tid = threadIdx.x, lane = tid & 63, wave = tid >> 6;
  int wr = wave >> 1, wc = wave & 1;
  for (int kt = 0; kt < DMODEL / 32; ++kt) {
    int k0 = kt * 32;
    if (kt) __syncthreads();
#pragma unroll
    for (int qi = 0; qi < 2; ++qi) {
      int e0 = (wave * 2 + qi) * 512;
      int e = e0 + lane * 8;
      gld_lds16(&A[(size_t)(brow0 + (e >> 5)) * DMODEL + k0 + (e & 31)], &As[e0]);
      gld_lds16(&Bt[(size_t)(bcol0 + (e >> 5)) * DMODEL + k0 + (e & 31)], &Bs[e0]);
    }
    __syncthreads();
    bf16x8 af[4], bff[4];
#pragma unroll
    for (int i = 0; i < 4; i++)
      af[i] = *(const bf16x8*)&As[(wr * 64 + i * 16 + (lane & 15)) * 32 + (lane >> 4) * 8];
#pragma unroll
    for (int j = 0; j < 4; j++)
      bff[j] = *(const bf16x8*)&Bs[(wc * 64 + j * 16 + (lane & 15)) * 32 + (lane >> 4) * 8];
#pragma unroll
    for (int i = 0; i < 4; i++)
#pragma unroll
      for (int j = 0; j < 4; j++)
        acc[i][j] = __builtin_amdgcn_mfma_f32_16x16x32_bf16(af[i], bff[j], acc[i][j], 0, 0, 0);
  }
}

// ---------------- flash attention (causal): unchanged from round 9 ----------------
__global__ __launch_bounds__(64, 2) void k_attn(const unsigned short* __restrict__ Qf,
                                                const unsigned short* __restrict__ Kf,
                                                const unsigned short* __restrict__ Vf,
                                                unsigned short* __restrict__ Ob) {
  int id = blockIdx.x;
  int xcd = id & 7, m = id >> 3;
  int bhl = m & 3, u = m >> 2;
  int bh = xcd * 4 + bhl;
  int v = (u < 32) ? (63 - u) : (u - 32);
  int nk = (v >> 1) + 1;
  int lane = threadIdx.x;
  int h = lane >> 5, ql = lane & 31;
  int qrow = v * 32 + ql;

  const unsigned short* Qp = Qf + (size_t)bh * 131072 + (size_t)v * 2048;
  const unsigned short* Kp = Kf + (size_t)bh * 131072;
  const unsigned short* Vp = Vf + (size_t)bh * 131072;
  int b = bh >> 4, hh = bh & 15;

  bf16x8 qv[4];
#pragma unroll
  for (int ds = 0; ds < 4; ds++)
    qv[ds] = *(const bf16x8*)&Qp[ds * 512 + lane * 8];

  bf16x8 Kr[8], Vr[8];
#pragma unroll
  for (int jj = 0; jj < 8; jj++) Kr[jj] = *(const bf16x8*)&Kp[jj * 512 + lane * 8];
#pragma unroll
  for (int jj = 0; jj < 8; jj++) Vr[jj] = *(const bf16x8*)&Vp[jj * 512 + lane * 8];

  f32x16 o0 = {}, o1 = {};
  float m_r = -3.0e38f, l_r = 0.0f;

#pragma unroll 1
  for (int kc = 0; kc < nk; ++kc) {
    f32x16 s0 = {}, s1 = {};
#pragma unroll
    for (int ds = 0; ds < 4; ds++) {
      s0 = __builtin_amdgcn_mfma_f32_32x32x16_bf16(Kr[ds], qv[ds], s0, 0, 0, 0);
      s1 = __builtin_amdgcn_mfma_f32_32x32x16_bf16(Kr[4 + ds], qv[ds], s1, 0, 0, 0);
    }
    bool pfn = (kc + 1 < nk);
    size_t nb = (size_t)(kc + 1) * 4096;
    if (pfn) {
#pragma unroll
      for (int jj = 0; jj < 8; jj++) Kr[jj] = *(const bf16x8*)&Kp[nb + jj * 512 + lane * 8];
    }
    int k0 = kc * 64;
    if (kc == nk - 1) {
#pragma unroll
      for (int r = 0; r < 16; r++) {
        int kloc = (r & 3) + 8 * (r >> 2) + 4 * h;
        if (k0 + kloc > qrow) s0[r] = -3.0e38f;
        if (k0 + 32 + kloc > qrow) s1[r] = -3.0e38f;
      }
    }
    float t0[8], t1[8];
#pragma unroll
    for (int r = 0; r < 8; r++) t0[r] = fmaxf(s0[r], s0[r + 8]);
#pragma unroll
    for (int r = 0; r < 8; r++) t1[r] = fmaxf(s1[r], s1[r + 8]);
#pragma unroll
    for (int r = 0; r < 4; r++) t0[r] = fmaxf(fmaxf(t0[r], t0[r + 4]), fmaxf(t1[r], t1[r + 4]));
    float pm = fmaxf(fmaxf(t0[0], t0[1]), fmaxf(t0[2], t0[3]));
    pm = fmaxf(pm, __shfl_xor(pm, 32));
    bool grow = pm > m_r + 8.0f;
    float mnew = grow ? pm : m_r;
    float sf = grow ? __builtin_amdgcn_exp2f(m_r - mnew) : 1.0f;
    m_r = mnew;
    float rsum = 0.0f;
#pragma unroll
    for (int r = 0; r < 16; r++) { s0[r] = __builtin_amdgcn_exp2f(s0[r] - m_r); rsum += s0[r]; }
#pragma unroll
    for (int r = 0; r < 16; r++) { s1[r] = __builtin_amdgcn_exp2f(s1[r] - m_r); rsum += s1[r]; }
    l_r = l_r * sf + rsum;
    if (__ballot(grow)) {
#pragma unroll
      for (int r = 0; r < 16; r++) { o0[r] *= sf; o1[r] *= sf; }
    }
    unsigned int pa0 = cvtpk_bf16(s0[0], s0[1]),   pa1 = cvtpk_bf16(s0[2], s0[3]);
    unsigned int pb0 = cvtpk_bf16(s0[4], s0[5]),   pb1 = cvtpk_bf16(s0[6], s0[7]);
    unsigned int pc0 = cvtpk_bf16(s0[8], s0[9]),   pc1 = cvtpk_bf16(s0[10], s0[11]);
    unsigned int pd0 = cvtpk_bf16(s0[12], s0[13]), pd1 = cvtpk_bf16(s0[14], s0[15]);
    unsigned int pe0 = cvtpk_bf16(s1[0], s1[1]),   pe1 = cvtpk_bf16(s1[2], s1[3]);
    unsigned int pf0 = cvtpk_bf16(s1[4], s1[5]),   pf1 = cvtpk_bf16(s1[6], s1[7]);
    unsigned int pg0 = cvtpk_bf16(s1[8], s1[9]),   pg1 = cvtpk_bf16(s1[10], s1[11]);
    unsigned int ph0 = cvtpk_bf16(s1[12], s1[13]), ph1 = cvtpk_bf16(s1[14], s1[15]);
    pl32swap(pa0, pb0); pl32swap(pa1, pb1);
    pl32swap(pc0, pd0); pl32swap(pc1, pd1);
    pl32swap(pe0, pf0); pl32swap(pe1, pf1);
    pl32swap(pg0, ph0); pl32swap(pg1, ph1);
    bf16x8 pfr[4];
    pfr[0] = __builtin_bit_cast(bf16x8, (u32x4){pa0, pa1, pb0, pb1});
    pfr[1] = __builtin_bit_cast(bf16x8, (u32x4){pc0, pc1, pd0, pd1});
    pfr[2] = __builtin_bit_cast(bf16x8, (u32x4){pe0, pe1, pf0, pf1});
    pfr[3] = __builtin_bit_cast(bf16x8, (u32x4){pg0, pg1, ph0, ph1});
#pragma unroll
    for (int ks = 0; ks < 4; ks++) {
      o0 = __builtin_amdgcn_mfma_f32_32x32x16_bf16(Vr[ks], pfr[ks], o0, 0, 0, 0);
      o1 = __builtin_amdgcn_mfma_f32_32x32x16_bf16(Vr[4 + ks], pfr[ks], o1, 0, 0, 0);
    }
    if (pfn) {
#pragma unroll
      for (int jj = 0; jj < 8; jj++) Vr[jj] = *(const bf16x8*)&Vp[nb + jj * 512 + lane * 8];
    }
  }

  float lt = l_r + __shfl_xor(l_r, 32);
  float rl = 1.0f / lt;
  size_t obase = ((size_t)(b * SEQ + qrow)) * DMODEL + hh * DHEAD;
#pragma unroll
  for (int rg = 0; rg < 4; rg++) {
    uint2 w0, w1;
    w0.x = cvtpk_bf16(o0[4 * rg] * rl, o0[4 * rg + 1] * rl);
    w0.y = cvtpk_bf16(o0[4 * rg + 2] * rl, o0[4 * rg + 3] * rl);
    w1.x = cvtpk_bf16(o1[4 * rg] * rl, o1[4 * rg + 1] * rl);
    w1.y = cvtpk_bf16(o1[4 * rg + 2] * rl, o1[4 * rg + 3] * rl);
    *(uint2*)&Ob[obase + 8 * rg + 4 * h] = w0;
    *(uint2*)&Ob[obase + 32 + 8 * rg + 4 * h] = w1;
  }
}

// ---------------- output projection (unchanged) ----------------
__global__ __launch_bounds__(256) void k_gemm_out(const unsigned short* __restrict__ Ob,
                                                  const unsigned short* __restrict__ Wot,
                                                  float* __restrict__ out) {
  __shared__ unsigned short As[128 * 32];
  __shared__ unsigned short Bs[128 * 32];
  int col0 = blockIdx.x * 128;
  int brow0 = blockIdx.y * 128;
  int lane = threadIdx.x & 63, wave = threadIdx.x >> 6;
  int wr = wave >> 1, wc = wave & 1;
  f32x4 acc[4][4] = {};
  gemm_core(Ob, Wot, brow0, col0, As, Bs, acc);
#pragma unroll
  for (int i = 0; i < 4; i++)
#pragma unroll
    for (int j = 0; j < 4; j++)
#pragma unroll
      for (int r = 0; r < 4; r++) {
        int row = brow0 + wr * 64 + i * 16 + ((lane >> 4) << 2) + r;
        int c = col0 + wc * 64 + j * 16 + (lane & 15);
        out[(size_t)row * DMODEL + c] = acc[i][j][r];
      }
}

extern "C" void kernel_launch(void* const* d_in, const int* in_sizes, int n_in,
                              void* d_out, int out_size, void* d_ws, size_t ws_size,
                              hipStream_t stream) {
  const float* x  = (const float*)d_in[0];
  const float* Wq = (const float*)d_in[1];
  const float* Wk = (const float*)d_in[2];
  const float* Wv = (const float*)d_in[3];
  const float* Wo = (const float*)d_in[4];
  float* out = (float*)d_out;
  char* ws = (char*)d_ws;
  unsigned short* Af  = (unsigned short*)(ws);
  unsigned short* Wqf = (unsigned short*)(ws + (8ull << 20));
  unsigned short* Wkf = (unsigned short*)(ws + (10ull << 20));
  unsigned short* Wvf = (unsigned short*)(ws + (12ull << 20));
  unsigned short* Wot = (unsigned short*)(ws + (14ull << 20));
  unsigned short* Qf  = (unsigned short*)(ws + (16ull << 20));
  unsigned short* Kf  = (unsigned short*)(ws + (24ull << 20));
  unsigned short* Vf  = (unsigned short*)(ws + (32ull << 20));
  unsigned short* Ob  = (unsigned short*)(ws + (40ull << 20));

  k_conv_x<<<dim3(2048), dim3(256), 0, stream>>>(x, Af);
  k_trans_wf<<<dim3(16, 32, 3), dim3(256), 0, stream>>>(Wq, Wk, Wv, Wqf, Wkf, Wvf);
  k_trans_wo<<<dim3(16, 16), dim3(256), 0, stream>>>(Wo, Wot);
  k_gemm_qkv<<<dim3(3072), dim3(64), 0, stream>>>(Af, Wqf, Wkf, Wvf, Qf, Kf, Vf);
  k_attn<<<dim3(2048), dim3(64), 0, stream>>>(Qf, Kf, Vf, Ob);
  k_gemm_out<<<dim3(8, 32), dim3(256), 0, stream>>>(Ob, Wot, out);
}

// Round 11
// 106.885 us; speedup vs baseline: 1.4056x; 1.0487x over previous
//
#include <hip/hip_runtime.h>

#define NHEAD 16
#define DHEAD 64
#define SEQ 2048
#define DMODEL 1024
#define BATCH 2
#define QSCALE 0.1803368801111204f  // 0.125 * log2(e): softmax runs in exp2 domain

typedef __bf16 bf16x8 __attribute__((ext_vector_type(8)));
typedef float f32x4 __attribute__((ext_vector_type(4)));
typedef float f32x16 __attribute__((ext_vector_type(16)));
typedef unsigned int u32x4 __attribute__((ext_vector_type(4)));

__device__ inline unsigned short f2bf(float f) {
  unsigned int u = __builtin_bit_cast(unsigned int, f);
  u = (u + 0x7FFFu + ((u >> 16) & 1u)) >> 16;
  return (unsigned short)u;
}

__device__ inline unsigned int cvtpk_bf16(float lo, float hi) {
  unsigned int r;
  asm("v_cvt_pk_bf16_f32 %0, %1, %2" : "=v"(r) : "v"(lo), "v"(hi));
  return r;
}

__device__ inline void pl32swap(unsigned int& a, unsigned int& b) {
  asm volatile("v_permlane32_swap_b32 %0, %1" : "+v"(a), "+v"(b));
}

typedef __attribute__((address_space(1))) unsigned int GU32;
typedef __attribute__((address_space(3))) unsigned int LU32;
__device__ inline void gld_lds16(const void* g, void* l) {
  __builtin_amdgcn_global_load_lds((GU32*)g, (LU32*)l, 16, 0, 0);
}

// ---------------- convert x to bf16, A-FRAGMENT-MAJOR ----------------
// Af[R(64)][kt(32)][i(4)][lane(64)][e(8)]: lane = ((k>>3)&3)*16 + (n&15), e = k&7, i = (n>>4)&3
__global__ __launch_bounds__(256) void k_conv_x(const float* __restrict__ x,
                                                unsigned short* __restrict__ Af) {
  int blk = blockIdx.x;           // 2048: R = blk>>5, kt = blk&31
  int R = blk >> 5, kt = blk & 31;
  int t = threadIdx.x;
  int i = t >> 6, lane = t & 63;
  int n = R * 64 + i * 16 + (lane & 15);
  int k = kt * 32 + (lane >> 4) * 8;
  const float* xp = x + (size_t)n * DMODEL + k;
  float4 v0 = *(const float4*)xp;
  float4 v1 = *(const float4*)(xp + 4);
  ushort4 lo, hi;
  lo.x = f2bf(v0.x); lo.y = f2bf(v0.y); lo.z = f2bf(v0.z); lo.w = f2bf(v0.w);
  hi.x = f2bf(v1.x); hi.y = f2bf(v1.y); hi.z = f2bf(v1.z); hi.w = f2bf(v1.w);
  size_t base = ((size_t)((R * 32 + kt) * 4 + i) * 64 + lane) * 8;
  *(ushort4*)&Af[base] = lo;
  *(ushort4*)&Af[base + 4] = hi;
}

// ---------------- Wq/Wk/Wv to B-FRAGMENT-MAJOR bf16 ----------------
// Wf[cb(16)][kt(32)][j(4)][lane(64)][e(8)]: lane = ((k>>3)&3)*16 + (c&15), e = k&7, j = (c>>4)&3
__global__ __launch_bounds__(256) void k_trans_wf(const float* __restrict__ Wq, const float* __restrict__ Wk,
                                                  const float* __restrict__ Wv,
                                                  unsigned short* __restrict__ Wqf, unsigned short* __restrict__ Wkf,
                                                  unsigned short* __restrict__ Wvf) {
  __shared__ float ts[32][65];
  int mat = blockIdx.z;
  const float* src = (mat == 0) ? Wq : (mat == 1) ? Wk : Wv;
  unsigned short* dst = (mat == 0) ? Wqf : (mat == 1) ? Wkf : Wvf;
  int cb = blockIdx.x, kt = blockIdx.y;
  int t = threadIdx.x;
  int row = t >> 3, seg = t & 7;
  const float* sp = src + (size_t)(kt * 32 + row) * DMODEL + cb * 64 + seg * 8;
  float4 u0 = *(const float4*)sp;
  float4 u1 = *(const float4*)(sp + 4);
  ts[row][seg * 8 + 0] = u0.x; ts[row][seg * 8 + 1] = u0.y;
  ts[row][seg * 8 + 2] = u0.z; ts[row][seg * 8 + 3] = u0.w;
  ts[row][seg * 8 + 4] = u1.x; ts[row][seg * 8 + 5] = u1.y;
  ts[row][seg * 8 + 6] = u1.z; ts[row][seg * 8 + 7] = u1.w;
  __syncthreads();
  int j = t >> 6, lane = t & 63;
  int c_l = j * 16 + (lane & 15);
  int kb = (lane >> 4) * 8;
  ushort4 lo, hi;
  lo.x = f2bf(ts[kb + 0][c_l]); lo.y = f2bf(ts[kb + 1][c_l]);
  lo.z = f2bf(ts[kb + 2][c_l]); lo.w = f2bf(ts[kb + 3][c_l]);
  hi.x = f2bf(ts[kb + 4][c_l]); hi.y = f2bf(ts[kb + 5][c_l]);
  hi.z = f2bf(ts[kb + 6][c_l]); hi.w = f2bf(ts[kb + 7][c_l]);
  size_t base = ((size_t)((cb * 32 + kt) * 4 + j) * 64 + lane) * 8;
  *(ushort4*)&dst[base] = lo;
  *(ushort4*)&dst[base + 4] = hi;
}

// ---------------- Wo transpose (old layout, for k_gemm_out) ----------------
__global__ __launch_bounds__(256) void k_trans_wo(const float* __restrict__ Wo,
                                                  unsigned short* __restrict__ Wot) {
  __shared__ float ts[64][65];
  int r0 = blockIdx.y * 64, c0 = blockIdx.x * 64;
  int t = threadIdx.x;
  int tr = t >> 4, tc = (t & 15) * 4;
#pragma unroll
  for (int i = 0; i < 4; i++) {
    int row = tr + i * 16;
    float4 v = *(const float4*)&Wo[(size_t)(r0 + row) * DMODEL + c0 + tc];
    ts[row][tc + 0] = v.x; ts[row][tc + 1] = v.y; ts[row][tc + 2] = v.z; ts[row][tc + 3] = v.w;
  }
  __syncthreads();
#pragma unroll
  for (int i = 0; i < 4; i++) {
    int nrow = tr + i * 16;
    ushort4 o;
    o.x = f2bf(ts[tc + 0][nrow]); o.y = f2bf(ts[tc + 1][nrow]);
    o.z = f2bf(ts[tc + 2][nrow]); o.w = f2bf(ts[tc + 3][nrow]);
    *(ushort4*)&Wot[(size_t)(c0 + nrow) * DMODEL + r0 + tc] = o;
  }
}

// ---------------- fused QKV projection: barrier-free, 64x128 tile/wave ----------------
// Grid 1536 = 8 XCD x (16 row-tiles x 12 col-tiles); per-XCD ws = 2MB A + 3MB B.
__global__ __launch_bounds__(64, 2) void k_gemm_qkv(const unsigned short* __restrict__ Af,
                                                    const unsigned short* __restrict__ Wqf,
                                                    const unsigned short* __restrict__ Wkf,
                                                    const unsigned short* __restrict__ Wvf,
                                                    unsigned short* __restrict__ Qf,
                                                    unsigned short* __restrict__ Kf,
                                                    unsigned short* __restrict__ Vf) {
  int id = blockIdx.x;            // 1536
  int xcd = id & 7, lid = id >> 3;          // 192 per XCD
  int rw = lid / 12, cw = lid % 12;         // cw fastest: adjacent blocks share A panel
  int R = (xcd >> 1) * 16 + rw;             // 0..63 row tile (64 rows)
  int ct = (xcd & 1) * 12 + cw;             // 0..23 col tile (128 cols over 3 mats)
  int mat = ct >> 3, cb2 = ct & 7;          // matrix, 128-col tile within
  const unsigned short* Bf = (mat == 0) ? Wqf : (mat == 1) ? Wkf : Wvf;
  int lane = threadIdx.x;
  const unsigned short* Ap  = Af + (size_t)R * 65536 + lane * 8;
  const unsigned short* Bp0 = Bf + (size_t)(cb2 * 2) * 65536 + lane * 8;
  const unsigned short* Bp1 = Bp0 + 65536;

  f32x4 acc[4][8] = {};
  bf16x8 a0[4], a1[4], b0[8], b1[8];
#pragma unroll
  for (int i = 0; i < 4; i++) a0[i] = *(const bf16x8*)(Ap + i * 512);
#pragma unroll
  for (int j = 0; j < 4; j++) {
    b0[j]     = *(const bf16x8*)(Bp0 + j * 512);
    b0[4 + j] = *(const bf16x8*)(Bp1 + j * 512);
  }
#pragma unroll 1
  for (int kt = 0; kt < 32; kt += 2) {
    {  // prefetch kt+1 into set 1
      const unsigned short* An = Ap + (kt + 1) * 2048;
      const unsigned short* Bn0 = Bp0 + (kt + 1) * 2048;
      const unsigned short* Bn1 = Bp1 + (kt + 1) * 2048;
#pragma unroll
      for (int i = 0; i < 4; i++) a1[i] = *(const bf16x8*)(An + i * 512);
#pragma unroll
      for (int j = 0; j < 4; j++) {
        b1[j]     = *(const bf16x8*)(Bn0 + j * 512);
        b1[4 + j] = *(const bf16x8*)(Bn1 + j * 512);
      }
    }
#pragma unroll
    for (int i = 0; i < 4; i++)
#pragma unroll
      for (int j = 0; j < 8; j++)
        acc[i][j] = __builtin_amdgcn_mfma_f32_16x16x32_bf16(a0[i], b0[j], acc[i][j], 0, 0, 0);
    if (kt + 2 < 32) {  // prefetch kt+2 into set 0
      const unsigned short* An = Ap + (kt + 2) * 2048;
      const unsigned short* Bn0 = Bp0 + (kt + 2) * 2048;
      const unsigned short* Bn1 = Bp1 + (kt + 2) * 2048;
#pragma unroll
      for (int i = 0; i < 4; i++) a0[i] = *(const bf16x8*)(An + i * 512);
#pragma unroll
      for (int j = 0; j < 4; j++) {
        b0[j]     = *(const bf16x8*)(Bn0 + j * 512);
        b0[4 + j] = *(const bf16x8*)(Bn1 + j * 512);
      }
    }
#pragma unroll
    for (int i = 0; i < 4; i++)
#pragma unroll
      for (int j = 0; j < 8; j++)
        acc[i][j] = __builtin_amdgcn_mfma_f32_16x16x32_bf16(a1[i], b1[j], acc[i][j], 0, 0, 0);
  }

  // ---- epilogue: fragment-major Qf/Kf/Vf writes (r9-verified formulas) ----
#pragma unroll
  for (int i = 0; i < 4; i++)
#pragma unroll
    for (int j = 0; j < 8; j++) {
      int n_g = R * 64 + i * 16 + ((lane >> 4) << 2);
      int c = cb2 * 128 + j * 16 + (lane & 15);   // within-matrix col 0..1023
      int b = n_g >> 11, n0 = n_g & 2047;
      int h = c >> 6, d = c & 63;
      int bh = b * NHEAD + h;
      if (mat == 0) {
        size_t base = ((size_t)(bh * 64 + (n0 >> 5)) * 4 + (d >> 4)) * 512 +
                      (size_t)((((d >> 3) & 1) * 32 + (n0 & 31)) * 8 + (d & 7));
#pragma unroll
        for (int r = 0; r < 4; r++) Qf[base + 8 * r] = f2bf(acc[i][j][r] * QSCALE);
      } else if (mat == 1) {
        size_t base = ((size_t)(bh * 32 + (n0 >> 6)) * 8 + ((d >> 4) + 4 * ((n0 >> 5) & 1))) * 512 +
                      (size_t)((((d >> 3) & 1) * 32 + (n0 & 31)) * 8 + (d & 7));
#pragma unroll
        for (int r = 0; r < 4; r++) Kf[base + 8 * r] = f2bf(acc[i][j][r]);
      } else {
        size_t base = ((size_t)(bh * 32 + (n0 >> 6)) * 8 + (((n0 >> 4) & 3) + 4 * (d >> 5))) * 512 +
                      (size_t)((((n0 >> 3) & 1) * 32 + (d & 31)) * 8 + (n0 & 7));
        ushort4 o;
        o.x = f2bf(acc[i][j][0]); o.y = f2bf(acc[i][j][1]);
        o.z = f2bf(acc[i][j][2]); o.w = f2bf(acc[i][j][3]);
        *(ushort4*)&Vf[base] = o;
      }
    }
}

// ---------------- GEMM core (m97-style) for output projection ----------------
__device__ inline void gemm_core(const unsigned short* __restrict__ A, const unsigned short* __restrict__ Bt,
                                 int brow0, int bcol0, unsigned short* As, unsigned short* Bs,
                                 f32x4 acc[4][4]) {
  int tid = threadIdx.x, lane = tid & 63, wave = tid >> 6;
  int wr = wave >> 1, wc = wave & 1;
  for (int kt = 0; kt < DMODEL / 32; ++kt) {
    int k0 = kt * 32;
    if (kt) __syncthreads();
#pragma unroll
    for (int qi = 0; qi < 2; ++qi) {
      int e0 = (wave * 2 + qi) * 512;
      int e = e0 + lane * 8;
      gld_lds16(&A[(size_t)(brow0 + (e >> 5)) * DMODEL + k0 + (e & 31)], &As[e0]);
      gld_lds16(&Bt[(size_t)(bcol0 + (e >> 5)) * DMODEL + k0 + (e & 31)], &Bs[e0]);
    }
    __syncthreads();
    bf16x8 af[4], bff[4];
#pragma unroll
    for (int i = 0; i < 4; i++)
      af[i] = *(const bf16x8*)&As[(wr * 64 + i * 16 + (lane & 15)) * 32 + (lane >> 4) * 8];
#pragma unroll
    for (int j = 0; j < 4; j++)
      bff[j] = *(const bf16x8*)&Bs[(wc * 64 + j * 16 + (lane & 15)) * 32 + (lane >> 4) * 8];
#pragma unroll
    for (int i = 0; i < 4; i++)
#pragma unroll
      for (int j = 0; j < 4; j++)
        acc[i][j] = __builtin_amdgcn_mfma_f32_16x16x32_bf16(af[i], bff[j], acc[i][j], 0, 0, 0);
  }
}

// ---------------- flash attention (causal): unchanged from round 9 ----------------
__global__ __launch_bounds__(64, 2) void k_attn(const unsigned short* __restrict__ Qf,
                                                const unsigned short* __restrict__ Kf,
                                                const unsigned short* __restrict__ Vf,
                                                unsigned short* __restrict__ Ob) {
  int id = blockIdx.x;
  int xcd = id & 7, m = id >> 3;
  int bhl = m & 3, u = m >> 2;
  int bh = xcd * 4 + bhl;
  int v = (u < 32) ? (63 - u) : (u - 32);
  int nk = (v >> 1) + 1;
  int lane = threadIdx.x;
  int h = lane >> 5, ql = lane & 31;
  int qrow = v * 32 + ql;

  const unsigned short* Qp = Qf + (size_t)bh * 131072 + (size_t)v * 2048;
  const unsigned short* Kp = Kf + (size_t)bh * 131072;
  const unsigned short* Vp = Vf + (size_t)bh * 131072;
  int b = bh >> 4, hh = bh & 15;

  bf16x8 qv[4];
#pragma unroll
  for (int ds = 0; ds < 4; ds++)
    qv[ds] = *(const bf16x8*)&Qp[ds * 512 + lane * 8];

  bf16x8 Kr[8], Vr[8];
#pragma unroll
  for (int jj = 0; jj < 8; jj++) Kr[jj] = *(const bf16x8*)&Kp[jj * 512 + lane * 8];
#pragma unroll
  for (int jj = 0; jj < 8; jj++) Vr[jj] = *(const bf16x8*)&Vp[jj * 512 + lane * 8];

  f32x16 o0 = {}, o1 = {};
  float m_r = -3.0e38f, l_r = 0.0f;

#pragma unroll 1
  for (int kc = 0; kc < nk; ++kc) {
    f32x16 s0 = {}, s1 = {};
#pragma unroll
    for (int ds = 0; ds < 4; ds++) {
      s0 = __builtin_amdgcn_mfma_f32_32x32x16_bf16(Kr[ds], qv[ds], s0, 0, 0, 0);
      s1 = __builtin_amdgcn_mfma_f32_32x32x16_bf16(Kr[4 + ds], qv[ds], s1, 0, 0, 0);
    }
    bool pfn = (kc + 1 < nk);
    size_t nb = (size_t)(kc + 1) * 4096;
    if (pfn) {
#pragma unroll
      for (int jj = 0; jj < 8; jj++) Kr[jj] = *(const bf16x8*)&Kp[nb + jj * 512 + lane * 8];
    }
    int k0 = kc * 64;
    if (kc == nk - 1) {
#pragma unroll
      for (int r = 0; r < 16; r++) {
        int kloc = (r & 3) + 8 * (r >> 2) + 4 * h;
        if (k0 + kloc > qrow) s0[r] = -3.0e38f;
        if (k0 + 32 + kloc > qrow) s1[r] = -3.0e38f;
      }
    }
    float t0[8], t1[8];
#pragma unroll
    for (int r = 0; r < 8; r++) t0[r] = fmaxf(s0[r], s0[r + 8]);
#pragma unroll
    for (int r = 0; r < 8; r++) t1[r] = fmaxf(s1[r], s1[r + 8]);
#pragma unroll
    for (int r = 0; r < 4; r++) t0[r] = fmaxf(fmaxf(t0[r], t0[r + 4]), fmaxf(t1[r], t1[r + 4]));
    float pm = fmaxf(fmaxf(t0[0], t0[1]), fmaxf(t0[2], t0[3]));
    pm = fmaxf(pm, __shfl_xor(pm, 32));
    bool grow = pm > m_r + 8.0f;
    float mnew = grow ? pm : m_r;
    float sf = grow ? __builtin_amdgcn_exp2f(m_r - mnew) : 1.0f;
    m_r = mnew;
    float rsum = 0.0f;
#pragma unroll
    for (int r = 0; r < 16; r++) { s0[r] = __builtin_amdgcn_exp2f(s0[r] - m_r); rsum += s0[r]; }
#pragma unroll
    for (int r = 0; r < 16; r++) { s1[r] = __builtin_amdgcn_exp2f(s1[r] - m_r); rsum += s1[r]; }
    l_r = l_r * sf + rsum;
    if (__ballot(grow)) {
#pragma unroll
      for (int r = 0; r < 16; r++) { o0[r] *= sf; o1[r] *= sf; }
    }
    unsigned int pa0 = cvtpk_bf16(s0[0], s0[1]),   pa1 = cvtpk_bf16(s0[2], s0[3]);
    unsigned int pb0 = cvtpk_bf16(s0[4], s0[5]),   pb1 = cvtpk_bf16(s0[6], s0[7]);
    unsigned int pc0 = cvtpk_bf16(s0[8], s0[9]),   pc1 = cvtpk_bf16(s0[10], s0[11]);
    unsigned int pd0 = cvtpk_bf16(s0[12], s0[13]), pd1 = cvtpk_bf16(s0[14], s0[15]);
    unsigned int pe0 = cvtpk_bf16(s1[0], s1[1]),   pe1 = cvtpk_bf16(s1[2], s1[3]);
    unsigned int pf0 = cvtpk_bf16(s1[4], s1[5]),   pf1 = cvtpk_bf16(s1[6], s1[7]);
    unsigned int pg0 = cvtpk_bf16(s1[8], s1[9]),   pg1 = cvtpk_bf16(s1[10], s1[11]);
    unsigned int ph0 = cvtpk_bf16(s1[12], s1[13]), ph1 = cvtpk_bf16(s1[14], s1[15]);
    pl32swap(pa0, pb0); pl32swap(pa1, pb1);
    pl32swap(pc0, pd0); pl32swap(pc1, pd1);
    pl32swap(pe0, pf0); pl32swap(pe1, pf1);
    pl32swap(pg0, ph0); pl32swap(pg1, ph1);
    bf16x8 pfr[4];
    pfr[0] = __builtin_bit_cast(bf16x8, (u32x4){pa0, pa1, pb0, pb1});
    pfr[1] = __builtin_bit_cast(bf16x8, (u32x4){pc0, pc1, pd0, pd1});
    pfr[2] = __builtin_bit_cast(bf16x8, (u32x4){pe0, pe1, pf0, pf1});
    pfr[3] = __builtin_bit_cast(bf16x8, (u32x4){pg0, pg1, ph0, ph1});
#pragma unroll
    for (int ks = 0; ks < 4; ks++) {
      o0 = __builtin_amdgcn_mfma_f32_32x32x16_bf16(Vr[ks], pfr[ks], o0, 0, 0, 0);
      o1 = __builtin_amdgcn_mfma_f32_32x32x16_bf16(Vr[4 + ks], pfr[ks], o1, 0, 0, 0);
    }
    if (pfn) {
#pragma unroll
      for (int jj = 0; jj < 8; jj++) Vr[jj] = *(const bf16x8*)&Vp[nb + jj * 512 + lane * 8];
    }
  }

  float lt = l_r + __shfl_xor(l_r, 32);
  float rl = 1.0f / lt;
  size_t obase = ((size_t)(b * SEQ + qrow)) * DMODEL + hh * DHEAD;
#pragma unroll
  for (int rg = 0; rg < 4; rg++) {
    uint2 w0, w1;
    w0.x = cvtpk_bf16(o0[4 * rg] * rl, o0[4 * rg + 1] * rl);
    w0.y = cvtpk_bf16(o0[4 * rg + 2] * rl, o0[4 * rg + 3] * rl);
    w1.x = cvtpk_bf16(o1[4 * rg] * rl, o1[4 * rg + 1] * rl);
    w1.y = cvtpk_bf16(o1[4 * rg + 2] * rl, o1[4 * rg + 3] * rl);
    *(uint2*)&Ob[obase + 8 * rg + 4 * h] = w0;
    *(uint2*)&Ob[obase + 32 + 8 * rg + 4 * h] = w1;
  }
}

// ---------------- output projection (unchanged) ----------------
__global__ __launch_bounds__(256) void k_gemm_out(const unsigned short* __restrict__ Ob,
                                                  const unsigned short* __restrict__ Wot,
                                                  float* __restrict__ out) {
  __shared__ unsigned short As[128 * 32];
  __shared__ unsigned short Bs[128 * 32];
  int col0 = blockIdx.x * 128;
  int brow0 = blockIdx.y * 128;
  int lane = threadIdx.x & 63, wave = threadIdx.x >> 6;
  int wr = wave >> 1, wc = wave & 1;
  f32x4 acc[4][4] = {};
  gemm_core(Ob, Wot, brow0, col0, As, Bs, acc);
#pragma unroll
  for (int i = 0; i < 4; i++)
#pragma unroll
    for (int j = 0; j < 4; j++)
#pragma unroll
      for (int r = 0; r < 4; r++) {
        int row = brow0 + wr * 64 + i * 16 + ((lane >> 4) << 2) + r;
        int c = col0 + wc * 64 + j * 16 + (lane & 15);
        out[(size_t)row * DMODEL + c] = acc[i][j][r];
      }
}

extern "C" void kernel_launch(void* const* d_in, const int* in_sizes, int n_in,
                              void* d_out, int out_size, void* d_ws, size_t ws_size,
                              hipStream_t stream) {
  const float* x  = (const float*)d_in[0];
  const float* Wq = (const float*)d_in[1];
  const float* Wk = (const float*)d_in[2];
  const float* Wv = (const float*)d_in[3];
  const float* Wo = (const float*)d_in[4];
  float* out = (float*)d_out;
  char* ws = (char*)d_ws;
  unsigned short* Af  = (unsigned short*)(ws);
  unsigned short* Wqf = (unsigned short*)(ws + (8ull << 20));
  unsigned short* Wkf = (unsigned short*)(ws + (10ull << 20));
  unsigned short* Wvf = (unsigned short*)(ws + (12ull << 20));
  unsigned short* Wot = (unsigned short*)(ws + (14ull << 20));
  unsigned short* Qf  = (unsigned short*)(ws + (16ull << 20));
  unsigned short* Kf  = (unsigned short*)(ws + (24ull << 20));
  unsigned short* Vf  = (unsigned short*)(ws + (32ull << 20));
  unsigned short* Ob  = (unsigned short*)(ws + (40ull << 20));

  k_conv_x<<<dim3(2048), dim3(256), 0, stream>>>(x, Af);
  k_trans_wf<<<dim3(16, 32, 3), dim3(256), 0, stream>>>(Wq, Wk, Wv, Wqf, Wkf, Wvf);
  k_trans_wo<<<dim3(16, 16), dim3(256), 0, stream>>>(Wo, Wot);
  k_gemm_qkv<<<dim3(1536), dim3(64), 0, stream>>>(Af, Wqf, Wkf, Wvf, Qf, Kf, Vf);
  k_attn<<<dim3(2048), dim3(64), 0, stream>>>(Qf, Kf, Vf, Ob);
  k_gemm_out<<<dim3(8, 32), dim3(256), 0, stream>>>(Ob, Wot, out);
}